// Round 1
// baseline (7809.062 us; speedup 1.0000x reference)
//
#include <hip/hip_runtime.h>
#include <math.h>

// Problem constants
#define Bc    4
#define NPGc  10000
#define EPGc  32000
#define MLc   128
#define NNc   40000      // N = B*NPG
#define NEc   128000     // E = B*EPG
#define E2c   16000      // EPG/2
#define ZETAc 1e-6f
#define INVPc 0.53995680345572354f   // 1/1.852
#define PEXPc 1.852f

__device__ __forceinline__ float selu_f(float x) {
    return 1.0507009873554805f * (x > 0.0f ? x : 1.6732632423543772f * expm1f(x));
}
// order-preserving float->uint map for atomicMax
__device__ __forceinline__ unsigned fmap(float f) {
    unsigned u = __float_as_uint(f);
    return (u & 0x80000000u) ? ~u : (u | 0x80000000u);
}
__device__ __forceinline__ float funmap(unsigned u) {
    return (u & 0x80000000u) ? __uint_as_float(u & 0x7fffffffu) : __uint_as_float(~u);
}
__device__ __forceinline__ float signf(float x) {
    return (x > 0.0f) ? 1.0f : (x < 0.0f ? -1.0f : 0.0f);
}

// ---------------- elementwise / scatter kernels ----------------

__global__ void k_zero_f(float* p, int n) {
    int i = blockIdx.x * 256 + threadIdx.x;
    if (i < n) p[i] = 0.0f;
}

__global__ void k_agg_init(unsigned* p, int n) {
    int i = blockIdx.x * 256 + threadIdx.x;
    if (i < n) p[i] = fmap(-3.0e38f);
}

// initial net flows from h_star (x[:,0]); writes q_hat, q_tilde, accumulates d_hat
__global__ void k_init_flows(const float* __restrict__ x, const float* __restrict__ r,
                             const int* __restrict__ sndr, const int* __restrict__ rcvr,
                             float* __restrict__ qh, float* __restrict__ qt,
                             float* __restrict__ dh) {
    int e = blockIdx.x * 256 + threadIdx.x;
    if (e >= NEc) return;
    float hv = x[2 * sndr[e]] - x[2 * rcvr[e]];
    float q = signf(hv) * powf((fabsf(hv) + ZETAc) / (r[e] + ZETAc), INVPc);
    qh[e] = q;
    qt[e] = q;
    atomicAdd(&dh[rcvr[e]], q);
}

// q_tilde from h_tilde
__global__ void k_flows_q(const float* __restrict__ h, const float* __restrict__ r,
                          const int* __restrict__ sndr, const int* __restrict__ rcvr,
                          float* __restrict__ qt) {
    int e = blockIdx.x * 256 + threadIdx.x;
    if (e >= NEc) return;
    float hv = h[sndr[e]] - h[rcvr[e]];
    qt[e] = signf(hv) * powf((fabsf(hv) + ZETAc) / (r[e] + ZETAc), INVPc);
}

// g = selu([d_hat, d_star]) @ W_node_in   (N x 128)
__global__ void k_node_in(const float* __restrict__ dh, const float* __restrict__ x,
                          const float* __restrict__ W, float* __restrict__ g) {
    int gid = blockIdx.x * 256 + threadIdx.x;   // N*128 exact
    int n = gid >> 7, c = gid & 127;
    float s0 = selu_f(dh[n]);
    float s1 = selu_f(x[2 * n + 1]);
    g[gid] = s0 * W[c] + s1 * W[MLc + c];
}

// z = selu([q_tilde, q_hat]) @ W_edge_in  (E x 128)
__global__ void k_edge_in(const float* __restrict__ qt, const float* __restrict__ qh,
                          const float* __restrict__ W, float* __restrict__ z) {
    int gid = blockIdx.x * 256 + threadIdx.x;   // E*128 exact
    int e = gid >> 7, c = gid & 127;
    z[gid] = selu_f(qt[e]) * W[c] + selu_f(qh[e]) * W[MLc + c];
}

// segment max of z rows into aggU (uint-mapped)
__global__ void k_seg_max_z(const float* __restrict__ z, const int* __restrict__ rcvr,
                            unsigned* __restrict__ aggU) {
    int gid = blockIdx.x * 256 + threadIdx.x;   // E*128 exact
    int e = gid >> 7, c = gid & 127;
    atomicMax(&aggU[(size_t)rcvr[e] * MLc + c], fmap(z[gid]));
}

__global__ void k_segsum(const float* __restrict__ qh, const int* __restrict__ rcvr,
                         float* __restrict__ dh) {
    int e = blockIdx.x * 256 + threadIdx.x;
    if (e >= NEc) return;
    atomicAdd(&dh[rcvr[e]], qh[e]);
}

// ---------------- head construction ----------------

__global__ void k_hl(const float* __restrict__ qh, const float* __restrict__ r,
                     float* __restrict__ hl) {
    int e = blockIdx.x * 256 + threadIdx.x;
    if (e >= NEc) return;
    float q = qh[e];
    hl[e] = r[e] * signf(q) * powf(fabsf(q), PEXPc);
}

__global__ void k_copy_h(const float* __restrict__ x, float* __restrict__ h) {
    int n = blockIdx.x * 256 + threadIdx.x;
    if (n < NNc) h[n] = x[2 * n];
}

__global__ void k_head_max(const float* __restrict__ h, const float* __restrict__ hl,
                           const int* __restrict__ sndr, const int* __restrict__ rcvr,
                           unsigned* __restrict__ aggU) {
    int e = blockIdx.x * 256 + threadIdx.x;
    if (e >= NEc) return;
    atomicMax(&aggU[rcvr[e]], fmap(h[sndr[e]] - hl[e]));
}

__global__ void k_head_update(const float* __restrict__ x, const unsigned* __restrict__ aggU,
                              float* __restrict__ h) {
    int n = blockIdx.x * 256 + threadIdx.x;
    if (n >= NNc) return;
    float hv = h[n];
    float a = funmap(aggU[n]);
    a = (a > -1e30f) ? a : hv;
    float hstar = x[2 * n];
    h[n] = (hstar != 0.0f) ? hstar : fmaxf(hv, a);
}

__global__ void k_out(const float* __restrict__ h, float* __restrict__ out) {
    int n = blockIdx.x * 256 + threadIdx.x;
    if (n < NNc) out[n] = h[n];
}

// ---------------- GEMM-ish fused MLP kernels ----------------
// 32-row tile, 256 threads, each thread owns a 4x4 block of the 32x128 output.
// LDS: input tile (<=32x384) ; intermediate 32x128 aliases the front of it.

// edge MLP: z[e] = selu(concat(g[sndr],g[rcvr],z[e])) @ We1 |> selu |> @ We2   (in-place z)
__global__ __launch_bounds__(256) void k_edge_mlp(
    const float* __restrict__ g, float* __restrict__ z,
    const float* __restrict__ W1, const float* __restrict__ W2,
    const int* __restrict__ sndr, const int* __restrict__ rcvr) {
    __shared__ float smem[32 * 384];             // 48 KB
    float* m_s = smem;                           // [32][384]
    float* t_s = smem;                           // [32][128] alias (front)
    const int tid = threadIdx.x;
    const int e0 = blockIdx.x * 32;

    for (int idx = tid; idx < 32 * 384; idx += 256) {
        int el = idx / 384, k = idx - el * 384;
        int e = e0 + el;
        float v;
        if (k < 128)       v = g[(size_t)sndr[e] * MLc + k];
        else if (k < 256)  v = g[(size_t)rcvr[e] * MLc + (k - 128)];
        else               v = z[(size_t)e * MLc + (k - 256)];
        m_s[idx] = selu_f(v);
    }
    __syncthreads();

    const int cg = (tid & 31) * 4;
    const int rg = (tid >> 5) * 4;
    float acc[4][4];
#pragma unroll
    for (int i = 0; i < 4; i++)
#pragma unroll
        for (int j = 0; j < 4; j++) acc[i][j] = 0.0f;

    for (int k = 0; k < 384; k++) {
        float4 b = *(const float4*)&W1[k * MLc + cg];
#pragma unroll
        for (int i = 0; i < 4; i++) {
            float a = m_s[(rg + i) * 384 + k];
            acc[i][0] += a * b.x; acc[i][1] += a * b.y;
            acc[i][2] += a * b.z; acc[i][3] += a * b.w;
        }
    }
    __syncthreads();   // everyone done reading m_s before t_s overwrite
#pragma unroll
    for (int i = 0; i < 4; i++)
#pragma unroll
        for (int j = 0; j < 4; j++) t_s[(rg + i) * 128 + cg + j] = selu_f(acc[i][j]);
    __syncthreads();

#pragma unroll
    for (int i = 0; i < 4; i++)
#pragma unroll
        for (int j = 0; j < 4; j++) acc[i][j] = 0.0f;
    for (int k = 0; k < 128; k++) {
        float4 b = *(const float4*)&W2[k * MLc + cg];
#pragma unroll
        for (int i = 0; i < 4; i++) {
            float a = t_s[(rg + i) * 128 + k];
            acc[i][0] += a * b.x; acc[i][1] += a * b.y;
            acc[i][2] += a * b.z; acc[i][3] += a * b.w;
        }
    }
#pragma unroll
    for (int i = 0; i < 4; i++) {
        float4 st = make_float4(acc[i][0], acc[i][1], acc[i][2], acc[i][3]);
        *(float4*)&z[(size_t)(e0 + rg + i) * MLc + cg] = st;
    }
}

// node MLP: g[n] = selu(selu(concat(g[n], agg[n])) @ Wn1) @ Wn2   (in-place g)
__global__ __launch_bounds__(256) void k_node_mlp(
    float* __restrict__ g, const unsigned* __restrict__ aggU,
    const float* __restrict__ W1, const float* __restrict__ W2) {
    __shared__ float smem[32 * 256];             // 32 KB
    float* m_s = smem;                           // [32][256]
    float* t_s = smem;                           // [32][128] alias
    const int tid = threadIdx.x;
    const int n0 = blockIdx.x * 32;

    for (int idx = tid; idx < 32 * 256; idx += 256) {
        int nl = idx >> 8, k = idx & 255;
        float v;
        if (k < 128) {
            v = g[(size_t)(n0 + nl) * MLc + k];
        } else {
            float a = funmap(aggU[(size_t)(n0 + nl) * MLc + (k - 128)]);
            v = (a > -1e30f) ? a : 0.0f;
        }
        m_s[idx] = selu_f(v);
    }
    __syncthreads();

    const int cg = (tid & 31) * 4;
    const int rg = (tid >> 5) * 4;
    float acc[4][4];
#pragma unroll
    for (int i = 0; i < 4; i++)
#pragma unroll
        for (int j = 0; j < 4; j++) acc[i][j] = 0.0f;

    for (int k = 0; k < 256; k++) {
        float4 b = *(const float4*)&W1[k * MLc + cg];
#pragma unroll
        for (int i = 0; i < 4; i++) {
            float a = m_s[(rg + i) * 256 + k];
            acc[i][0] += a * b.x; acc[i][1] += a * b.y;
            acc[i][2] += a * b.z; acc[i][3] += a * b.w;
        }
    }
    __syncthreads();
#pragma unroll
    for (int i = 0; i < 4; i++)
#pragma unroll
        for (int j = 0; j < 4; j++) t_s[(rg + i) * 128 + cg + j] = selu_f(acc[i][j]);
    __syncthreads();

#pragma unroll
    for (int i = 0; i < 4; i++)
#pragma unroll
        for (int j = 0; j < 4; j++) acc[i][j] = 0.0f;
    for (int k = 0; k < 128; k++) {
        float4 b = *(const float4*)&W2[k * MLc + cg];
#pragma unroll
        for (int i = 0; i < 4; i++) {
            float a = t_s[(rg + i) * 128 + k];
            acc[i][0] += a * b.x; acc[i][1] += a * b.y;
            acc[i][2] += a * b.z; acc[i][3] += a * b.w;
        }
    }
#pragma unroll
    for (int i = 0; i < 4; i++) {
        float4 st = make_float4(acc[i][0], acc[i][1], acc[i][2], acc[i][3]);
        *(float4*)&g[(size_t)(n0 + rg + i) * MLc + cg] = st;
    }
}

// Wf chain on FIRST-HALF edges only: q_new = q_old + selu(selu(lam@Wf1)@Wf2)@Wf3
// then q[e]=q_new, q[e+E2]=-q_new (antisymmetrization).
__global__ __launch_bounds__(256) void k_wf(
    const float* __restrict__ g, const float* __restrict__ z,
    const float* __restrict__ W1, const float* __restrict__ W2,
    const float* __restrict__ W3,
    const int* __restrict__ sndr, const int* __restrict__ rcvr,
    float* __restrict__ qh) {
    __shared__ float smem[32 * 384];
    float* m_s = smem;
    float* t_s = smem;
    const int tid = threadIdx.x;
    const int fi0 = blockIdx.x * 32;

    for (int idx = tid; idx < 32 * 384; idx += 256) {
        int el = idx / 384, k = idx - el * 384;
        int fi = fi0 + el;
        int b = fi / E2c;
        int e = b * EPGc + (fi - b * E2c);
        float v;
        if (k < 128)       v = g[(size_t)sndr[e] * MLc + k];
        else if (k < 256)  v = g[(size_t)rcvr[e] * MLc + (k - 128)];
        else               v = z[(size_t)e * MLc + (k - 256)];
        m_s[idx] = selu_f(v);
    }
    __syncthreads();

    const int cg = (tid & 31) * 4;
    const int rg = (tid >> 5) * 4;
    float acc[4][4];
#pragma unroll
    for (int i = 0; i < 4; i++)
#pragma unroll
        for (int j = 0; j < 4; j++) acc[i][j] = 0.0f;

    for (int k = 0; k < 384; k++) {
        float4 b = *(const float4*)&W1[k * MLc + cg];
#pragma unroll
        for (int i = 0; i < 4; i++) {
            float a = m_s[(rg + i) * 384 + k];
            acc[i][0] += a * b.x; acc[i][1] += a * b.y;
            acc[i][2] += a * b.z; acc[i][3] += a * b.w;
        }
    }
    __syncthreads();
#pragma unroll
    for (int i = 0; i < 4; i++)
#pragma unroll
        for (int j = 0; j < 4; j++) t_s[(rg + i) * 128 + cg + j] = selu_f(acc[i][j]);
    __syncthreads();

#pragma unroll
    for (int i = 0; i < 4; i++)
#pragma unroll
        for (int j = 0; j < 4; j++) acc[i][j] = 0.0f;
    for (int k = 0; k < 128; k++) {
        float4 b = *(const float4*)&W2[k * MLc + cg];
#pragma unroll
        for (int i = 0; i < 4; i++) {
            float a = t_s[(rg + i) * 128 + k];
            acc[i][0] += a * b.x; acc[i][1] += a * b.y;
            acc[i][2] += a * b.z; acc[i][3] += a * b.w;
        }
    }
    // f[row] = sum_c selu(out[row][c]) * W3[c]; partial over this thread's 4 cols
    float p[4];
#pragma unroll
    for (int i = 0; i < 4; i++) {
        p[i] = selu_f(acc[i][0]) * W3[cg + 0] + selu_f(acc[i][1]) * W3[cg + 1] +
               selu_f(acc[i][2]) * W3[cg + 2] + selu_f(acc[i][3]) * W3[cg + 3];
    }
    // reduce across the 32 col-group lanes (lane bits 0..4 only)
#pragma unroll
    for (int off = 1; off < 32; off <<= 1) {
#pragma unroll
        for (int i = 0; i < 4; i++) p[i] += __shfl_xor(p[i], off, 64);
    }
    if ((tid & 31) == 0) {
#pragma unroll
        for (int i = 0; i < 4; i++) {
            int fi = fi0 + rg + i;
            int b = fi / E2c;
            int j = fi - b * E2c;
            int e = b * EPGc + j;
            float qn = qh[e] + p[i];
            qh[e] = qn;
            qh[e + E2c] = -qn;
        }
    }
}

// ---------------- host-side orchestration ----------------

extern "C" void kernel_launch(void* const* d_in, const int* in_sizes, int n_in,
                              void* d_out, int out_size, void* d_ws, size_t ws_size,
                              hipStream_t stream) {
    const float* x   = (const float*)d_in[0];
    const float* r   = (const float*)d_in[1];
    const float* Wni = (const float*)d_in[2];
    const float* Wei = (const float*)d_in[3];
    const float* Wf1 = (const float*)d_in[4];
    const float* Wf2 = (const float*)d_in[5];
    const float* Wf3 = (const float*)d_in[6];
    const float* We1 = (const float*)d_in[7];   // (3, 384, 128)
    const float* We2 = (const float*)d_in[8];   // (3, 128, 128)
    const float* Wn1 = (const float*)d_in[9];   // (3, 256, 128)
    const float* Wn2 = (const float*)d_in[10];  // (3, 128, 128)
    const int* sndr  = (const int*)d_in[11];
    const int* rcvr  = (const int*)d_in[12];
    float* out = (float*)d_out;

    char* ws = (char*)d_ws;
    float* g      = (float*)ws;  ws += (size_t)NNc * MLc * 4;
    float* z      = (float*)ws;  ws += (size_t)NEc * MLc * 4;
    unsigned* agg = (unsigned*)ws; ws += (size_t)NNc * MLc * 4;
    float* qh     = (float*)ws;  ws += (size_t)NEc * 4;
    float* qt     = (float*)ws;  ws += (size_t)NEc * 4;
    float* dh     = (float*)ws;  ws += (size_t)NNc * 4;
    float* hl     = (float*)ws;  ws += (size_t)NEc * 4;
    float* h      = (float*)ws;  ws += (size_t)NNc * 4;

    const int TB = 256;
    const int gN   = (NNc + TB - 1) / TB;
    const int gE   = (NEc + TB - 1) / TB;
    const int gNM  = NNc * MLc / TB;    // exact
    const int gEM  = NEc * MLc / TB;    // exact

    // initial flows: d_hat, q_hat, q_tilde from h_star
    k_zero_f<<<gN, TB, 0, stream>>>(dh, NNc);
    k_init_flows<<<gE, TB, 0, stream>>>(x, r, sndr, rcvr, qh, qt, dh);

    for (int kit = 0; kit < 4; kit++) {
        k_node_in<<<gNM, TB, 0, stream>>>(dh, x, Wni, g);
        k_edge_in<<<gEM, TB, 0, stream>>>(qt, qh, Wei, z);
        for (int i = 0; i < 3; i++) {
            k_edge_mlp<<<NEc / 32, TB, 0, stream>>>(g, z, We1 + (size_t)i * 384 * MLc,
                                                    We2 + (size_t)i * MLc * MLc, sndr, rcvr);
            k_agg_init<<<gNM, TB, 0, stream>>>(agg, NNc * MLc);
            k_seg_max_z<<<gEM, TB, 0, stream>>>(z, rcvr, agg);
            k_node_mlp<<<NNc / 32, TB, 0, stream>>>(g, agg, Wn1 + (size_t)i * 256 * MLc,
                                                    Wn2 + (size_t)i * MLc * MLc);
        }
        k_wf<<<(Bc * E2c) / 32, TB, 0, stream>>>(g, z, Wf1, Wf2, Wf3, sndr, rcvr, qh);
        // d_hat = segment_sum(q_hat)
        k_zero_f<<<gN, TB, 0, stream>>>(dh, NNc);
        k_segsum<<<gE, TB, 0, stream>>>(qh, rcvr, dh);
        // construct heads
        k_hl<<<gE, TB, 0, stream>>>(qh, r, hl);
        k_copy_h<<<gN, TB, 0, stream>>>(x, h);
        for (int jh = 0; jh < 6; jh++) {
            k_agg_init<<<gN, TB, 0, stream>>>(agg, NNc);
            k_head_max<<<gE, TB, 0, stream>>>(h, hl, sndr, rcvr, agg);
            k_head_update<<<gN, TB, 0, stream>>>(x, agg, h);
        }
        // q_tilde for next iteration
        k_flows_q<<<gE, TB, 0, stream>>>(h, r, sndr, rcvr, qt);
    }
    k_out<<<gN, TB, 0, stream>>>(h, out);
}

// Round 3
// 5990.646 us; speedup vs baseline: 1.3035x; 1.3035x over previous
//
#include <hip/hip_runtime.h>
#include <hip/hip_bf16.h>
#include <math.h>

// Problem constants
#define NPGc  10000
#define EPGc  32000
#define MLc   128
#define NNc   40000      // N
#define NEc   128000     // E
#define E2c   16000      // EPG/2
#define ZETAc 1e-6f
#define INVPc 0.53995680345572354f   // 1/1.852
#define PEXPc 1.852f

typedef __attribute__((ext_vector_type(8))) short short8;   // 8 bf16 (4 VGPRs)
typedef __attribute__((ext_vector_type(4))) float f32x4;    // MFMA acc

__device__ __forceinline__ float selu_f(float x) {
    return 1.0507009873554805f * (x > 0.0f ? x : 1.6732632423543772f * expm1f(x));
}
__device__ __forceinline__ short f2bf(float f) {
    __hip_bfloat16 b = __float2bfloat16(f);   // RNE
    return *reinterpret_cast<short*>(&b);
}
// split fp32 -> (hi, lo) bf16 pair: v ~= hi + lo, residual ~2^-18 relative
__device__ __forceinline__ void splitu(float v, unsigned& hi, unsigned& lo) {
    __hip_bfloat16 h = __float2bfloat16(v);
    hi = (unsigned short)*reinterpret_cast<short*>(&h);
    float rem = v - __bfloat162float(h);
    __hip_bfloat16 l = __float2bfloat16(rem);
    lo = (unsigned short)*reinterpret_cast<short*>(&l);
}
__device__ __forceinline__ float signf(float x) {
    return (x > 0.0f) ? 1.0f : (x < 0.0f ? -1.0f : 0.0f);
}

// ---------------- weight convert+transpose+split: dst[n][k] = split(src[k][n]) ----------------
__global__ void k_wconv2(const float* __restrict__ src, short* __restrict__ dh,
                         short* __restrict__ dl, int K) {
    int gid = blockIdx.x * 256 + threadIdx.x;
    if (gid >= 128 * K) return;
    int n = gid / K, k = gid - n * K;
    unsigned h, l;
    splitu(src[k * 128 + n], h, l);
    dh[n * K + k] = (short)h;
    dl[n * K + k] = (short)l;
}

// ---------------- CSR build (by rcvr) ----------------
__global__ void k_zero_i(int* p, int n) {
    int i = blockIdx.x * 256 + threadIdx.x;
    if (i < n) p[i] = 0;
}
__global__ void k_count(const int* __restrict__ rcvr, int* __restrict__ deg) {
    int e = blockIdx.x * 256 + threadIdx.x;
    if (e < NEc) atomicAdd(&deg[rcvr[e]], 1);
}
// single-block chunked exclusive scan -> rowstart + cursor copy
__global__ void k_scan(const int* __restrict__ deg, int* __restrict__ rowstart,
                       int* __restrict__ cursor) {
    __shared__ int sums[256];
    const int tid = threadIdx.x;
    const int CH = (NNc + 255) / 256;
    const int i0 = tid * CH;
    int s = 0;
    for (int j = 0; j < CH; j++) {
        int i = i0 + j;
        if (i < NNc) s += deg[i];
    }
    sums[tid] = s;
    __syncthreads();
    for (int off = 1; off < 256; off <<= 1) {
        int t = (tid >= off) ? sums[tid - off] : 0;
        __syncthreads();
        sums[tid] += t;
        __syncthreads();
    }
    int base = sums[tid] - s;   // exclusive prefix of this chunk
    for (int j = 0; j < CH; j++) {
        int i = i0 + j;
        if (i < NNc) {
            rowstart[i] = base;
            cursor[i] = base;
            base += deg[i];
        }
    }
    if (tid == 255) rowstart[NNc] = base;
}
__global__ void k_scatter(const int* __restrict__ sndr, const int* __restrict__ rcvr,
                          int* __restrict__ cursor, int2* __restrict__ csr_se) {
    int e = blockIdx.x * 256 + threadIdx.x;
    if (e >= NEc) return;
    int rv = rcvr[e];
    int p = atomicAdd(&cursor[rv], 1);
    csr_se[p] = make_int2(sndr[e], e);
}

// ---------------- flows / elementwise ----------------
__global__ void k_qinit(const float* __restrict__ x, const float* __restrict__ r,
                        const int* __restrict__ sndr, const int* __restrict__ rcvr,
                        float* __restrict__ qh, float* __restrict__ qt) {
    int e = blockIdx.x * 256 + threadIdx.x;
    if (e >= NEc) return;
    float hv = x[2 * sndr[e]] - x[2 * rcvr[e]];
    float q = signf(hv) * powf((fabsf(hv) + ZETAc) / (r[e] + ZETAc), INVPc);
    qh[e] = q; qt[e] = q;
}
__global__ void k_flows_q(const float* __restrict__ h, const float* __restrict__ r,
                          const int* __restrict__ sndr, const int* __restrict__ rcvr,
                          float* __restrict__ qt) {
    int e = blockIdx.x * 256 + threadIdx.x;
    if (e >= NEc) return;
    float hv = h[sndr[e]] - h[rcvr[e]];
    qt[e] = signf(hv) * powf((fabsf(hv) + ZETAc) / (r[e] + ZETAc), INVPc);
}
__global__ void k_segsum_csr(const float* __restrict__ qh, const int* __restrict__ rowstart,
                             const int2* __restrict__ csr_se, float* __restrict__ dh) {
    int n = blockIdx.x * 256 + threadIdx.x;
    if (n >= NNc) return;
    float s = 0.0f;
    int p0 = rowstart[n], p1 = rowstart[n + 1];
    for (int p = p0; p < p1; p++) s += qh[csr_se[p].y];
    dh[n] = s;
}
__global__ void k_node_in(const float* __restrict__ dh, const float* __restrict__ x,
                          const float* __restrict__ W, float* __restrict__ g) {
    int gid = blockIdx.x * 256 + threadIdx.x;   // N*128 exact
    int n = gid >> 7, c = gid & 127;
    g[gid] = selu_f(dh[n]) * W[c] + selu_f(x[2 * n + 1]) * W[MLc + c];
}
__global__ void k_edge_in(const float* __restrict__ qt, const float* __restrict__ qh,
                          const float* __restrict__ W, float* __restrict__ z) {
    int gid = blockIdx.x * 256 + threadIdx.x;   // E*128 exact
    int e = gid >> 7, c = gid & 127;
    z[gid] = selu_f(qt[e]) * W[c] + selu_f(qh[e]) * W[MLc + c];
}
// segment max of z rows via CSR gather; writes post-where value (0 for empty)
__global__ void k_seg_max_csr(const float* __restrict__ z, const int* __restrict__ rowstart,
                              const int2* __restrict__ csr_se, float* __restrict__ agg) {
    int gid = blockIdx.x * 256 + threadIdx.x;   // N*128 exact
    int n = gid >> 7, c = gid & 127;
    int p0 = rowstart[n], p1 = rowstart[n + 1];
    float m = -3.0e38f;
    for (int p = p0; p < p1; p++) m = fmaxf(m, z[(size_t)csr_se[p].y * MLc + c]);
    agg[gid] = (m > -1e30f) ? m : 0.0f;
}
__global__ void k_hl(const float* __restrict__ qh, const float* __restrict__ r,
                     float* __restrict__ hl) {
    int e = blockIdx.x * 256 + threadIdx.x;
    if (e >= NEc) return;
    float q = qh[e];
    hl[e] = r[e] * signf(q) * powf(fabsf(q), PEXPc);
}
__global__ void k_copy_h(const float* __restrict__ x, float* __restrict__ h) {
    int n = blockIdx.x * 256 + threadIdx.x;
    if (n < NNc) h[n] = x[2 * n];
}
// one head-propagation iteration, CSR gather, ping-pong
__global__ void k_head_iter(const float* __restrict__ x, const float* __restrict__ hin,
                            const float* __restrict__ hl, const int* __restrict__ rowstart,
                            const int2* __restrict__ csr_se, float* __restrict__ hout) {
    int n = blockIdx.x * 256 + threadIdx.x;
    if (n >= NNc) return;
    float hv = hin[n];
    float m = -3.0e38f;
    int p0 = rowstart[n], p1 = rowstart[n + 1];
    for (int p = p0; p < p1; p++) {
        int2 se = csr_se[p];
        m = fmaxf(m, hin[se.x] - hl[se.y]);
    }
    float a = (m > -1e30f) ? m : hv;
    float hstar = x[2 * n];
    hout[n] = (hstar != 0.0f) ? hstar : fmaxf(hv, a);
}
__global__ void k_out(const float* __restrict__ h, float* __restrict__ out) {
    int n = blockIdx.x * 256 + threadIdx.x;
    if (n < NNc) out[n] = h[n];
}

// ---------------- split-bf16 MFMA MLP kernels ----------------
// Emulated-fp32 GEMM: A*B ~= Ah*Bh + Al*Bh + Ah*Bl (fp32 acc), rel err ~2^-18.
// 32-row tile, 4 waves: rb=w&1 (16-row block), ch=w>>1 (64-col half, 4 tiles).
// A-frag: row=lane&15, k=quad*8+j (ds_read_b128). B from bf16 transposed W [n][k].
// C/D: col=lane&15, row=quad*4+reg.
// LDS strides padded so row stride % 32 dwords == 4 (rotates banks); 16B aligned.

#define MS_E 392   // 384+8 shorts
#define MS_N 264   // 256+8
#define TS   136   // 128+8

__global__ __launch_bounds__(256) void k_edge_mlp_mfma(
    const float* __restrict__ g, float* __restrict__ z,
    const short* __restrict__ W1h, const short* __restrict__ W1l,
    const short* __restrict__ W2h, const short* __restrict__ W2l,
    const int* __restrict__ sndr, const int* __restrict__ rcvr) {
    __shared__ short smem[2 * 32 * MS_E];        // 50176 B
    short* m_hi = smem;
    short* m_lo = smem + 32 * MS_E;
    short* t_hi = smem;                          // alias front of m_hi (post-barrier)
    short* t_lo = smem + 32 * TS;
    const int tid = threadIdx.x;
    const int e0 = blockIdx.x * 32;

    for (int idx = tid; idx < 32 * 192; idx += 256) {
        int row = idx / 192, pp = idx - row * 192, k = 2 * pp;
        int e = e0 + row;
        float2 v;
        if (k < 128)       v = *(const float2*)&g[(size_t)sndr[e] * MLc + k];
        else if (k < 256)  v = *(const float2*)&g[(size_t)rcvr[e] * MLc + (k - 128)];
        else               v = *(const float2*)&z[(size_t)e * MLc + (k - 256)];
        unsigned h0, l0, h1, l1;
        splitu(selu_f(v.x), h0, l0);
        splitu(selu_f(v.y), h1, l1);
        *(unsigned*)&m_hi[row * MS_E + k] = h0 | (h1 << 16);
        *(unsigned*)&m_lo[row * MS_E + k] = l0 | (l1 << 16);
    }
    __syncthreads();

    const int lane = tid & 63, wave = tid >> 6;
    const int rb = wave & 1, ch = wave >> 1;
    const int l15 = lane & 15, quad = lane >> 4;

    f32x4 acc[4];
#pragma unroll
    for (int t = 0; t < 4; t++) acc[t] = (f32x4){0.f, 0.f, 0.f, 0.f};
    const short* ah_p = &m_hi[(rb * 16 + l15) * MS_E + quad * 8];
    const short* al_p = &m_lo[(rb * 16 + l15) * MS_E + quad * 8];
#pragma unroll 4
    for (int kc = 0; kc < 12; kc++) {
        short8 ah = *(const short8*)(ah_p + kc * 32);
        short8 al = *(const short8*)(al_p + kc * 32);
#pragma unroll
        for (int t = 0; t < 4; t++) {
            size_t wo = (size_t)(ch * 64 + t * 16 + l15) * 384 + kc * 32 + quad * 8;
            short8 bh = *(const short8*)&W1h[wo];
            short8 bl = *(const short8*)&W1l[wo];
            acc[t] = __builtin_amdgcn_mfma_f32_16x16x32_bf16(ah, bh, acc[t], 0, 0, 0);
            acc[t] = __builtin_amdgcn_mfma_f32_16x16x32_bf16(al, bh, acc[t], 0, 0, 0);
            acc[t] = __builtin_amdgcn_mfma_f32_16x16x32_bf16(ah, bl, acc[t], 0, 0, 0);
        }
    }
    __syncthreads();   // all GEMM1 reads of m_* done before t alias overwrite
#pragma unroll
    for (int t = 0; t < 4; t++) {
        int col = ch * 64 + t * 16 + l15;
#pragma unroll
        for (int rr = 0; rr < 4; rr++) {
            unsigned h, l;
            splitu(selu_f(acc[t][rr]), h, l);
            t_hi[(rb * 16 + quad * 4 + rr) * TS + col] = (short)h;
            t_lo[(rb * 16 + quad * 4 + rr) * TS + col] = (short)l;
        }
    }
    __syncthreads();

    f32x4 acc2[4];
#pragma unroll
    for (int t = 0; t < 4; t++) acc2[t] = (f32x4){0.f, 0.f, 0.f, 0.f};
    const short* a2h = &t_hi[(rb * 16 + l15) * TS + quad * 8];
    const short* a2l = &t_lo[(rb * 16 + l15) * TS + quad * 8];
#pragma unroll
    for (int kc = 0; kc < 4; kc++) {
        short8 ah = *(const short8*)(a2h + kc * 32);
        short8 al = *(const short8*)(a2l + kc * 32);
#pragma unroll
        for (int t = 0; t < 4; t++) {
            size_t wo = (size_t)(ch * 64 + t * 16 + l15) * 128 + kc * 32 + quad * 8;
            short8 bh = *(const short8*)&W2h[wo];
            short8 bl = *(const short8*)&W2l[wo];
            acc2[t] = __builtin_amdgcn_mfma_f32_16x16x32_bf16(ah, bh, acc2[t], 0, 0, 0);
            acc2[t] = __builtin_amdgcn_mfma_f32_16x16x32_bf16(al, bh, acc2[t], 0, 0, 0);
            acc2[t] = __builtin_amdgcn_mfma_f32_16x16x32_bf16(ah, bl, acc2[t], 0, 0, 0);
        }
    }
#pragma unroll
    for (int t = 0; t < 4; t++) {
        int col = ch * 64 + t * 16 + l15;
#pragma unroll
        for (int rr = 0; rr < 4; rr++)
            z[(size_t)(e0 + rb * 16 + quad * 4 + rr) * MLc + col] = acc2[t][rr];
    }
}

__global__ __launch_bounds__(256) void k_node_mlp_mfma(
    float* __restrict__ g, const float* __restrict__ agg,
    const short* __restrict__ W1h, const short* __restrict__ W1l,
    const short* __restrict__ W2h, const short* __restrict__ W2l) {
    __shared__ short smem[2 * 32 * MS_N];        // 33792 B
    short* m_hi = smem;
    short* m_lo = smem + 32 * MS_N;
    short* t_hi = smem;
    short* t_lo = smem + 32 * TS;
    const int tid = threadIdx.x;
    const int n0 = blockIdx.x * 32;

    for (int idx = tid; idx < 32 * 128; idx += 256) {
        int row = idx >> 7, pp = idx & 127, k = 2 * pp;
        float2 v;
        if (k < 128) v = *(const float2*)&g[(size_t)(n0 + row) * MLc + k];
        else         v = *(const float2*)&agg[(size_t)(n0 + row) * MLc + (k - 128)];
        unsigned h0, l0, h1, l1;
        splitu(selu_f(v.x), h0, l0);
        splitu(selu_f(v.y), h1, l1);
        *(unsigned*)&m_hi[row * MS_N + k] = h0 | (h1 << 16);
        *(unsigned*)&m_lo[row * MS_N + k] = l0 | (l1 << 16);
    }
    __syncthreads();

    const int lane = tid & 63, wave = tid >> 6;
    const int rb = wave & 1, ch = wave >> 1;
    const int l15 = lane & 15, quad = lane >> 4;

    f32x4 acc[4];
#pragma unroll
    for (int t = 0; t < 4; t++) acc[t] = (f32x4){0.f, 0.f, 0.f, 0.f};
    const short* ah_p = &m_hi[(rb * 16 + l15) * MS_N + quad * 8];
    const short* al_p = &m_lo[(rb * 16 + l15) * MS_N + quad * 8];
#pragma unroll 4
    for (int kc = 0; kc < 8; kc++) {
        short8 ah = *(const short8*)(ah_p + kc * 32);
        short8 al = *(const short8*)(al_p + kc * 32);
#pragma unroll
        for (int t = 0; t < 4; t++) {
            size_t wo = (size_t)(ch * 64 + t * 16 + l15) * 256 + kc * 32 + quad * 8;
            short8 bh = *(const short8*)&W1h[wo];
            short8 bl = *(const short8*)&W1l[wo];
            acc[t] = __builtin_amdgcn_mfma_f32_16x16x32_bf16(ah, bh, acc[t], 0, 0, 0);
            acc[t] = __builtin_amdgcn_mfma_f32_16x16x32_bf16(al, bh, acc[t], 0, 0, 0);
            acc[t] = __builtin_amdgcn_mfma_f32_16x16x32_bf16(ah, bl, acc[t], 0, 0, 0);
        }
    }
    __syncthreads();
#pragma unroll
    for (int t = 0; t < 4; t++) {
        int col = ch * 64 + t * 16 + l15;
#pragma unroll
        for (int rr = 0; rr < 4; rr++) {
            unsigned h, l;
            splitu(selu_f(acc[t][rr]), h, l);
            t_hi[(rb * 16 + quad * 4 + rr) * TS + col] = (short)h;
            t_lo[(rb * 16 + quad * 4 + rr) * TS + col] = (short)l;
        }
    }
    __syncthreads();

    f32x4 acc2[4];
#pragma unroll
    for (int t = 0; t < 4; t++) acc2[t] = (f32x4){0.f, 0.f, 0.f, 0.f};
    const short* a2h = &t_hi[(rb * 16 + l15) * TS + quad * 8];
    const short* a2l = &t_lo[(rb * 16 + l15) * TS + quad * 8];
#pragma unroll
    for (int kc = 0; kc < 4; kc++) {
        short8 ah = *(const short8*)(a2h + kc * 32);
        short8 al = *(const short8*)(a2l + kc * 32);
#pragma unroll
        for (int t = 0; t < 4; t++) {
            size_t wo = (size_t)(ch * 64 + t * 16 + l15) * 128 + kc * 32 + quad * 8;
            short8 bh = *(const short8*)&W2h[wo];
            short8 bl = *(const short8*)&W2l[wo];
            acc2[t] = __builtin_amdgcn_mfma_f32_16x16x32_bf16(ah, bh, acc2[t], 0, 0, 0);
            acc2[t] = __builtin_amdgcn_mfma_f32_16x16x32_bf16(al, bh, acc2[t], 0, 0, 0);
            acc2[t] = __builtin_amdgcn_mfma_f32_16x16x32_bf16(ah, bl, acc2[t], 0, 0, 0);
        }
    }
#pragma unroll
    for (int t = 0; t < 4; t++) {
        int col = ch * 64 + t * 16 + l15;
#pragma unroll
        for (int rr = 0; rr < 4; rr++)
            g[(size_t)(n0 + rb * 16 + quad * 4 + rr) * MLc + col] = acc2[t][rr];
    }
}

// Wf chain on first-half edges: q_new = q_old + selu(selu(lam@Wf1)@Wf2)@Wf3; antisymmetrize.
__global__ __launch_bounds__(256) void k_wf_mfma(
    const float* __restrict__ g, const float* __restrict__ z,
    const short* __restrict__ W1h, const short* __restrict__ W1l,
    const short* __restrict__ W2h, const short* __restrict__ W2l,
    const float* __restrict__ W3 /*[128]*/,
    const int* __restrict__ sndr, const int* __restrict__ rcvr,
    float* __restrict__ qh) {
    __shared__ short smem[2 * 32 * MS_E];
    __shared__ float red[64];
    short* m_hi = smem;
    short* m_lo = smem + 32 * MS_E;
    short* t_hi = smem;
    short* t_lo = smem + 32 * TS;
    const int tid = threadIdx.x;
    const int fi0 = blockIdx.x * 32;
    const int b = fi0 / E2c;                  // block never straddles a batch (E2%32==0)
    const int ebase = b * EPGc - b * E2c;     // e = ebase + fi

    for (int idx = tid; idx < 32 * 192; idx += 256) {
        int row = idx / 192, pp = idx - row * 192, k = 2 * pp;
        int e = ebase + fi0 + row;
        float2 v;
        if (k < 128)       v = *(const float2*)&g[(size_t)sndr[e] * MLc + k];
        else if (k < 256)  v = *(const float2*)&g[(size_t)rcvr[e] * MLc + (k - 128)];
        else               v = *(const float2*)&z[(size_t)e * MLc + (k - 256)];
        unsigned h0, l0, h1, l1;
        splitu(selu_f(v.x), h0, l0);
        splitu(selu_f(v.y), h1, l1);
        *(unsigned*)&m_hi[row * MS_E + k] = h0 | (h1 << 16);
        *(unsigned*)&m_lo[row * MS_E + k] = l0 | (l1 << 16);
    }
    __syncthreads();

    const int lane = tid & 63, wave = tid >> 6;
    const int rb = wave & 1, ch = wave >> 1;
    const int l15 = lane & 15, quad = lane >> 4;

    f32x4 acc[4];
#pragma unroll
    for (int t = 0; t < 4; t++) acc[t] = (f32x4){0.f, 0.f, 0.f, 0.f};
    const short* ah_p = &m_hi[(rb * 16 + l15) * MS_E + quad * 8];
    const short* al_p = &m_lo[(rb * 16 + l15) * MS_E + quad * 8];
#pragma unroll 4
    for (int kc = 0; kc < 12; kc++) {
        short8 ah = *(const short8*)(ah_p + kc * 32);
        short8 al = *(const short8*)(al_p + kc * 32);
#pragma unroll
        for (int t = 0; t < 4; t++) {
            size_t wo = (size_t)(ch * 64 + t * 16 + l15) * 384 + kc * 32 + quad * 8;
            short8 bh = *(const short8*)&W1h[wo];
            short8 bl = *(const short8*)&W1l[wo];
            acc[t] = __builtin_amdgcn_mfma_f32_16x16x32_bf16(ah, bh, acc[t], 0, 0, 0);
            acc[t] = __builtin_amdgcn_mfma_f32_16x16x32_bf16(al, bh, acc[t], 0, 0, 0);
            acc[t] = __builtin_amdgcn_mfma_f32_16x16x32_bf16(ah, bl, acc[t], 0, 0, 0);
        }
    }
    __syncthreads();
#pragma unroll
    for (int t = 0; t < 4; t++) {
        int col = ch * 64 + t * 16 + l15;
#pragma unroll
        for (int rr = 0; rr < 4; rr++) {
            unsigned h, l;
            splitu(selu_f(acc[t][rr]), h, l);
            t_hi[(rb * 16 + quad * 4 + rr) * TS + col] = (short)h;
            t_lo[(rb * 16 + quad * 4 + rr) * TS + col] = (short)l;
        }
    }
    __syncthreads();

    f32x4 acc2[4];
#pragma unroll
    for (int t = 0; t < 4; t++) acc2[t] = (f32x4){0.f, 0.f, 0.f, 0.f};
    const short* a2h = &t_hi[(rb * 16 + l15) * TS + quad * 8];
    const short* a2l = &t_lo[(rb * 16 + l15) * TS + quad * 8];
#pragma unroll
    for (int kc = 0; kc < 4; kc++) {
        short8 ah = *(const short8*)(a2h + kc * 32);
        short8 al = *(const short8*)(a2l + kc * 32);
#pragma unroll
        for (int t = 0; t < 4; t++) {
            size_t wo = (size_t)(ch * 64 + t * 16 + l15) * 128 + kc * 32 + quad * 8;
            short8 bh = *(const short8*)&W2h[wo];
            short8 bl = *(const short8*)&W2l[wo];
            acc2[t] = __builtin_amdgcn_mfma_f32_16x16x32_bf16(ah, bh, acc2[t], 0, 0, 0);
            acc2[t] = __builtin_amdgcn_mfma_f32_16x16x32_bf16(al, bh, acc2[t], 0, 0, 0);
            acc2[t] = __builtin_amdgcn_mfma_f32_16x16x32_bf16(ah, bl, acc2[t], 0, 0, 0);
        }
    }
    // per-lane partial of sum_c selu(out[row][c]) * W3[c]
    float p[4] = {0.f, 0.f, 0.f, 0.f};
#pragma unroll
    for (int t = 0; t < 4; t++) {
        float w3 = W3[ch * 64 + t * 16 + l15];
#pragma unroll
        for (int rr = 0; rr < 4; rr++) p[rr] += selu_f(acc2[t][rr]) * w3;
    }
#pragma unroll
    for (int off = 1; off < 16; off <<= 1) {
#pragma unroll
        for (int rr = 0; rr < 4; rr++) p[rr] += __shfl_xor(p[rr], off, 64);
    }
    if (l15 == 0) {
#pragma unroll
        for (int rr = 0; rr < 4; rr++) red[(rb * 16 + quad * 4 + rr) * 2 + ch] = p[rr];
    }
    __syncthreads();
    if (tid < 32) {
        float f = red[tid * 2] + red[tid * 2 + 1];
        int e = ebase + fi0 + tid;
        float qn = qh[e] + f;
        qh[e] = qn;
        qh[e + E2c] = -qn;
    }
}

// ---------------- host orchestration ----------------

extern "C" void kernel_launch(void* const* d_in, const int* in_sizes, int n_in,
                              void* d_out, int out_size, void* d_ws, size_t ws_size,
                              hipStream_t stream) {
    const float* x   = (const float*)d_in[0];
    const float* r   = (const float*)d_in[1];
    const float* Wni = (const float*)d_in[2];
    const float* Wei = (const float*)d_in[3];
    const float* Wf1 = (const float*)d_in[4];
    const float* Wf2 = (const float*)d_in[5];
    const float* Wf3 = (const float*)d_in[6];
    const float* We1 = (const float*)d_in[7];   // (3,384,128)
    const float* We2 = (const float*)d_in[8];   // (3,128,128)
    const float* Wn1 = (const float*)d_in[9];   // (3,256,128)
    const float* Wn2 = (const float*)d_in[10];  // (3,128,128)
    const int* sndr  = (const int*)d_in[11];
    const int* rcvr  = (const int*)d_in[12];
    float* out = (float*)d_out;

    char* wp = (char*)d_ws;
    auto carve = [&](size_t bytes) -> void* {
        void* ret = (void*)wp;
        wp += (bytes + 255) & ~(size_t)255;
        return ret;
    };
    float* g      = (float*)carve((size_t)NNc * MLc * 4);
    float* z      = (float*)carve((size_t)NEc * MLc * 4);
    float* agg    = (float*)carve((size_t)NNc * MLc * 4);
    float* qh     = (float*)carve((size_t)NEc * 4);
    float* qt     = (float*)carve((size_t)NEc * 4);
    float* dh     = (float*)carve((size_t)NNc * 4);
    float* hl     = (float*)carve((size_t)NEc * 4);
    float* hA     = (float*)carve((size_t)NNc * 4);
    float* hB     = (float*)carve((size_t)NNc * 4);
    int*   deg    = (int*)carve((size_t)NNc * 4);
    int*   cursor = (int*)carve((size_t)NNc * 4);
    int*   rowst  = (int*)carve((size_t)(NNc + 1) * 4);
    int2*  csr_se = (int2*)carve((size_t)NEc * 8);
    short* we1h   = (short*)carve((size_t)3 * 128 * 384 * 2);
    short* we1l   = (short*)carve((size_t)3 * 128 * 384 * 2);
    short* we2h   = (short*)carve((size_t)3 * 128 * 128 * 2);
    short* we2l   = (short*)carve((size_t)3 * 128 * 128 * 2);
    short* wn1h   = (short*)carve((size_t)3 * 128 * 256 * 2);
    short* wn1l   = (short*)carve((size_t)3 * 128 * 256 * 2);
    short* wn2h   = (short*)carve((size_t)3 * 128 * 128 * 2);
    short* wn2l   = (short*)carve((size_t)3 * 128 * 128 * 2);
    short* wf1h   = (short*)carve((size_t)128 * 384 * 2);
    short* wf1l   = (short*)carve((size_t)128 * 384 * 2);
    short* wf2h   = (short*)carve((size_t)128 * 128 * 2);
    short* wf2l   = (short*)carve((size_t)128 * 128 * 2);

    const int TB = 256;
    const int gN  = (NNc + TB - 1) / TB;
    const int gE  = (NEc + TB - 1) / TB;
    const int gNM = NNc * MLc / TB;

    // weight bf16 hi/lo transposed copies
    for (int i = 0; i < 3; i++) {
        k_wconv2<<<(128 * 384 + 255) / 256, TB, 0, stream>>>(We1 + (size_t)i * 384 * 128, we1h + (size_t)i * 128 * 384, we1l + (size_t)i * 128 * 384, 384);
        k_wconv2<<<(128 * 128 + 255) / 256, TB, 0, stream>>>(We2 + (size_t)i * 128 * 128, we2h + (size_t)i * 128 * 128, we2l + (size_t)i * 128 * 128, 128);
        k_wconv2<<<(128 * 256 + 255) / 256, TB, 0, stream>>>(Wn1 + (size_t)i * 256 * 128, wn1h + (size_t)i * 128 * 256, wn1l + (size_t)i * 128 * 256, 256);
        k_wconv2<<<(128 * 128 + 255) / 256, TB, 0, stream>>>(Wn2 + (size_t)i * 128 * 128, wn2h + (size_t)i * 128 * 128, wn2l + (size_t)i * 128 * 128, 128);
    }
    k_wconv2<<<(128 * 384 + 255) / 256, TB, 0, stream>>>(Wf1, wf1h, wf1l, 384);
    k_wconv2<<<(128 * 128 + 255) / 256, TB, 0, stream>>>(Wf2, wf2h, wf2l, 128);

    // CSR build
    k_zero_i<<<gN, TB, 0, stream>>>(deg, NNc);
    k_count<<<gE, TB, 0, stream>>>(rcvr, deg);
    k_scan<<<1, TB, 0, stream>>>(deg, rowst, cursor);
    k_scatter<<<gE, TB, 0, stream>>>(sndr, rcvr, cursor, csr_se);

    // initial flows
    k_qinit<<<gE, TB, 0, stream>>>(x, r, sndr, rcvr, qh, qt);
    k_segsum_csr<<<gN, TB, 0, stream>>>(qh, rowst, csr_se, dh);

    float* hcur = hA;
    float* hnxt = hB;
    for (int kit = 0; kit < 4; kit++) {
        k_node_in<<<gNM, TB, 0, stream>>>(dh, x, Wni, g);
        k_edge_in<<<NEc * MLc / TB, TB, 0, stream>>>(qt, qh, Wei, z);
        for (int i = 0; i < 3; i++) {
            k_edge_mlp_mfma<<<NEc / 32, TB, 0, stream>>>(g, z,
                we1h + (size_t)i * 128 * 384, we1l + (size_t)i * 128 * 384,
                we2h + (size_t)i * 128 * 128, we2l + (size_t)i * 128 * 128, sndr, rcvr);
            k_seg_max_csr<<<gNM, TB, 0, stream>>>(z, rowst, csr_se, agg);
            k_node_mlp_mfma<<<NNc / 32, TB, 0, stream>>>(g, agg,
                wn1h + (size_t)i * 128 * 256, wn1l + (size_t)i * 128 * 256,
                wn2h + (size_t)i * 128 * 128, wn2l + (size_t)i * 128 * 128);
        }
        k_wf_mfma<<<(4 * E2c) / 32, TB, 0, stream>>>(g, z, wf1h, wf1l, wf2h, wf2l,
                                                     Wf3, sndr, rcvr, qh);
        k_segsum_csr<<<gN, TB, 0, stream>>>(qh, rowst, csr_se, dh);
        // heads
        k_hl<<<gE, TB, 0, stream>>>(qh, r, hl);
        k_copy_h<<<gN, TB, 0, stream>>>(x, hcur);
        for (int jh = 0; jh < 6; jh++) {
            k_head_iter<<<gN, TB, 0, stream>>>(x, hcur, hl, rowst, csr_se, hnxt);
            float* tmp = hcur; hcur = hnxt; hnxt = tmp;
        }
        k_flows_q<<<gE, TB, 0, stream>>>(hcur, r, sndr, rcvr, qt);
    }
    k_out<<<gN, TB, 0, stream>>>(hcur, out);
}

// Round 4
// 3584.702 us; speedup vs baseline: 2.1784x; 1.6712x over previous
//
#include <hip/hip_runtime.h>
#include <hip/hip_bf16.h>
#include <math.h>

// Problem constants
#define NPGc  10000
#define EPGc  32000
#define MLc   128
#define NNc   40000      // N
#define NEc   128000     // E
#define E2c   16000      // EPG/2
#define ZETAc 1e-6f
#define INVPc 0.53995680345572354f   // 1/1.852
#define PEXPc 1.852f

typedef __attribute__((ext_vector_type(8))) short short8;   // 8 bf16 (4 VGPRs)
typedef __attribute__((ext_vector_type(4))) float f32x4;    // MFMA acc

// fast selu: __expf -> v_exp_f32; error ~1ulp, far below bf16-grade threshold
__device__ __forceinline__ float selu_f(float x) {
    float e = __expf(x) - 1.0f;
    return 1.0507009873554805f * (x > 0.0f ? x : 1.6732632423543772f * e);
}
// split fp32 -> (hi, lo) bf16 pair: v ~= hi + lo, residual ~2^-18 relative
__device__ __forceinline__ void splitu(float v, unsigned& hi, unsigned& lo) {
    __hip_bfloat16 h = __float2bfloat16(v);
    hi = (unsigned short)*reinterpret_cast<short*>(&h);
    float rem = v - __bfloat162float(h);
    __hip_bfloat16 l = __float2bfloat16(rem);
    lo = (unsigned short)*reinterpret_cast<short*>(&l);
}
__device__ __forceinline__ float signf(float x) {
    return (x > 0.0f) ? 1.0f : (x < 0.0f ? -1.0f : 0.0f);
}

// ---------------- weight convert+transpose+split: dst[n][k] = split(src[k][n]) ----------------
__global__ void k_wconv2(const float* __restrict__ src, short* __restrict__ dh,
                         short* __restrict__ dl, int K) {
    int gid = blockIdx.x * 256 + threadIdx.x;
    if (gid >= 128 * K) return;
    int n = gid / K, k = gid - n * K;
    unsigned h, l;
    splitu(src[k * 128 + n], h, l);
    dh[n * K + k] = (short)h;
    dl[n * K + k] = (short)l;
}

// ---------------- CSR build (by rcvr) ----------------
__global__ void k_zero_i(int* p, int n) {
    int i = blockIdx.x * 256 + threadIdx.x;
    if (i < n) p[i] = 0;
}
__global__ void k_count(const int* __restrict__ rcvr, int* __restrict__ deg) {
    int e = blockIdx.x * 256 + threadIdx.x;
    if (e < NEc) atomicAdd(&deg[rcvr[e]], 1);
}
// single-block chunked exclusive scan -> rowstart + cursor copy
__global__ void k_scan(const int* __restrict__ deg, int* __restrict__ rowstart,
                       int* __restrict__ cursor) {
    __shared__ int sums[256];
    const int tid = threadIdx.x;
    const int CH = (NNc + 255) / 256;
    const int i0 = tid * CH;
    int s = 0;
    for (int j = 0; j < CH; j++) {
        int i = i0 + j;
        if (i < NNc) s += deg[i];
    }
    sums[tid] = s;
    __syncthreads();
    for (int off = 1; off < 256; off <<= 1) {
        int t = (tid >= off) ? sums[tid - off] : 0;
        __syncthreads();
        sums[tid] += t;
        __syncthreads();
    }
    int base = sums[tid] - s;   // exclusive prefix of this chunk
    for (int j = 0; j < CH; j++) {
        int i = i0 + j;
        if (i < NNc) {
            rowstart[i] = base;
            cursor[i] = base;
            base += deg[i];
        }
    }
    if (tid == 255) rowstart[NNc] = base;
}
__global__ void k_scatter(const int* __restrict__ sndr, const int* __restrict__ rcvr,
                          int* __restrict__ cursor, int2* __restrict__ csr_se) {
    int e = blockIdx.x * 256 + threadIdx.x;
    if (e >= NEc) return;
    int rv = rcvr[e];
    int p = atomicAdd(&cursor[rv], 1);
    csr_se[p] = make_int2(sndr[e], e);
}

// ---------------- flows / elementwise ----------------
__global__ void k_qinit(const float* __restrict__ x, const float* __restrict__ r,
                        const int* __restrict__ sndr, const int* __restrict__ rcvr,
                        float* __restrict__ qh, float* __restrict__ qt) {
    int e = blockIdx.x * 256 + threadIdx.x;
    if (e >= NEc) return;
    float hv = x[2 * sndr[e]] - x[2 * rcvr[e]];
    float q = signf(hv) * __powf((fabsf(hv) + ZETAc) / (r[e] + ZETAc), INVPc);
    qh[e] = q; qt[e] = q;
}
__global__ void k_flows_q(const float* __restrict__ h, const float* __restrict__ r,
                          const int* __restrict__ sndr, const int* __restrict__ rcvr,
                          float* __restrict__ qt) {
    int e = blockIdx.x * 256 + threadIdx.x;
    if (e >= NEc) return;
    float hv = h[sndr[e]] - h[rcvr[e]];
    qt[e] = signf(hv) * __powf((fabsf(hv) + ZETAc) / (r[e] + ZETAc), INVPc);
}
__global__ void k_segsum_csr(const float* __restrict__ qh, const int* __restrict__ rowstart,
                             const int2* __restrict__ csr_se, float* __restrict__ dh) {
    int n = blockIdx.x * 256 + threadIdx.x;
    if (n >= NNc) return;
    float s = 0.0f;
    int p0 = rowstart[n], p1 = rowstart[n + 1];
    for (int p = p0; p < p1; p++) s += qh[csr_se[p].y];
    dh[n] = s;
}
__global__ void k_node_in(const float* __restrict__ dh, const float* __restrict__ x,
                          const float* __restrict__ W, float* __restrict__ g) {
    int gid = blockIdx.x * 256 + threadIdx.x;   // N*128 exact
    int n = gid >> 7, c = gid & 127;
    g[gid] = selu_f(dh[n]) * W[c] + selu_f(x[2 * n + 1]) * W[MLc + c];
}
__global__ void k_edge_in(const float* __restrict__ qt, const float* __restrict__ qh,
                          const float* __restrict__ W, float* __restrict__ z) {
    int gid = blockIdx.x * 256 + threadIdx.x;   // E*128 exact
    int e = gid >> 7, c = gid & 127;
    z[gid] = selu_f(qt[e]) * W[c] + selu_f(qh[e]) * W[MLc + c];
}
__global__ void k_hl(const float* __restrict__ qh, const float* __restrict__ r,
                     float* __restrict__ hl) {
    int e = blockIdx.x * 256 + threadIdx.x;
    if (e >= NEc) return;
    float q = qh[e];
    hl[e] = r[e] * signf(q) * __powf(fabsf(q), PEXPc);
}
__global__ void k_copy_h(const float* __restrict__ x, float* __restrict__ h) {
    int n = blockIdx.x * 256 + threadIdx.x;
    if (n < NNc) h[n] = x[2 * n];
}
// one head-propagation iteration, CSR gather, ping-pong
__global__ void k_head_iter(const float* __restrict__ x, const float* __restrict__ hin,
                            const float* __restrict__ hl, const int* __restrict__ rowstart,
                            const int2* __restrict__ csr_se, float* __restrict__ hout) {
    int n = blockIdx.x * 256 + threadIdx.x;
    if (n >= NNc) return;
    float hv = hin[n];
    float m = -3.0e38f;
    int p0 = rowstart[n], p1 = rowstart[n + 1];
    for (int p = p0; p < p1; p++) {
        int2 se = csr_se[p];
        m = fmaxf(m, hin[se.x] - hl[se.y]);
    }
    float a = (m > -1e30f) ? m : hv;
    float hstar = x[2 * n];
    hout[n] = (hstar != 0.0f) ? hstar : fmaxf(hv, a);
}
__global__ void k_out(const float* __restrict__ h, float* __restrict__ out) {
    int n = blockIdx.x * 256 + threadIdx.x;
    if (n < NNc) out[n] = h[n];
}

// ---------------- split-bf16 MFMA MLP kernels ----------------
// Emulated-fp32 GEMM: A*B ~= Ah*Bh + Al*Bh + Ah*Bl (fp32 acc), rel err ~2^-18.
// 32-row tile, 512 threads = 8 waves. Wave w owns col-tile ct=w (16 cols) and
// BOTH 16-row tiles -> each B fragment feeds 6 MFMAs (2x reuse vs r3).
// A-frag: row=lane&15, k=quad*8+j (ds_read_b128). B from bf16 transposed W [n][k].
// C/D: col=lane&15, row=quad*4+reg.

#define MS_E 392   // 384+8 shorts
#define MS_N 264   // 256+8
#define TS   136   // 128+8

__global__ __launch_bounds__(512) void k_edge_mlp_mfma(
    const float* __restrict__ g, float* __restrict__ z,
    const short* __restrict__ W1h, const short* __restrict__ W1l,
    const short* __restrict__ W2h, const short* __restrict__ W2l,
    const int* __restrict__ sndr, const int* __restrict__ rcvr) {
    __shared__ short smem[2 * 32 * MS_E];        // 50176 B -> 3 blocks/CU, 24 waves
    short* m_hi = smem;
    short* m_lo = smem + 32 * MS_E;
    short* t_hi = smem;                          // alias front of m_hi (post-barrier)
    short* t_lo = smem + 32 * TS;
    const int tid = threadIdx.x;
    const int e0 = blockIdx.x * 32;

    for (int idx = tid; idx < 32 * 192; idx += 512) {
        int row = idx / 192, pp = idx - row * 192, k = 2 * pp;
        int e = e0 + row;
        float2 v;
        if (k < 128)       v = *(const float2*)&g[(size_t)sndr[e] * MLc + k];
        else if (k < 256)  v = *(const float2*)&g[(size_t)rcvr[e] * MLc + (k - 128)];
        else               v = *(const float2*)&z[(size_t)e * MLc + (k - 256)];
        unsigned h0, l0, h1, l1;
        splitu(selu_f(v.x), h0, l0);
        splitu(selu_f(v.y), h1, l1);
        *(unsigned*)&m_hi[row * MS_E + k] = h0 | (h1 << 16);
        *(unsigned*)&m_lo[row * MS_E + k] = l0 | (l1 << 16);
    }
    __syncthreads();

    const int lane = tid & 63, ct = tid >> 6;    // wave = col-tile
    const int l15 = lane & 15, quad = lane >> 4;

    f32x4 acc[2];
    acc[0] = (f32x4){0.f, 0.f, 0.f, 0.f};
    acc[1] = (f32x4){0.f, 0.f, 0.f, 0.f};
#pragma unroll 4
    for (int kc = 0; kc < 12; kc++) {
        size_t wo = (size_t)(ct * 16 + l15) * 384 + kc * 32 + quad * 8;
        short8 bh = *(const short8*)&W1h[wo];
        short8 bl = *(const short8*)&W1l[wo];
#pragma unroll
        for (int rt = 0; rt < 2; rt++) {
            const short* ap = &m_hi[(rt * 16 + l15) * MS_E + kc * 32 + quad * 8];
            short8 ah = *(const short8*)ap;
            short8 al = *(const short8*)(ap + 32 * MS_E);
            acc[rt] = __builtin_amdgcn_mfma_f32_16x16x32_bf16(ah, bh, acc[rt], 0, 0, 0);
            acc[rt] = __builtin_amdgcn_mfma_f32_16x16x32_bf16(al, bh, acc[rt], 0, 0, 0);
            acc[rt] = __builtin_amdgcn_mfma_f32_16x16x32_bf16(ah, bl, acc[rt], 0, 0, 0);
        }
    }
    __syncthreads();   // all GEMM1 reads of m_* done before t alias overwrite
#pragma unroll
    for (int rt = 0; rt < 2; rt++) {
        int col = ct * 16 + l15;
#pragma unroll
        for (int rr = 0; rr < 4; rr++) {
            unsigned h, l;
            splitu(selu_f(acc[rt][rr]), h, l);
            t_hi[(rt * 16 + quad * 4 + rr) * TS + col] = (short)h;
            t_lo[(rt * 16 + quad * 4 + rr) * TS + col] = (short)l;
        }
    }
    __syncthreads();

    f32x4 acc2[2];
    acc2[0] = (f32x4){0.f, 0.f, 0.f, 0.f};
    acc2[1] = (f32x4){0.f, 0.f, 0.f, 0.f};
#pragma unroll
    for (int kc = 0; kc < 4; kc++) {
        size_t wo = (size_t)(ct * 16 + l15) * 128 + kc * 32 + quad * 8;
        short8 bh = *(const short8*)&W2h[wo];
        short8 bl = *(const short8*)&W2l[wo];
#pragma unroll
        for (int rt = 0; rt < 2; rt++) {
            const short* ap = &t_hi[(rt * 16 + l15) * TS + kc * 32 + quad * 8];
            short8 ah = *(const short8*)ap;
            short8 al = *(const short8*)(ap + 32 * TS);
            acc2[rt] = __builtin_amdgcn_mfma_f32_16x16x32_bf16(ah, bh, acc2[rt], 0, 0, 0);
            acc2[rt] = __builtin_amdgcn_mfma_f32_16x16x32_bf16(al, bh, acc2[rt], 0, 0, 0);
            acc2[rt] = __builtin_amdgcn_mfma_f32_16x16x32_bf16(ah, bl, acc2[rt], 0, 0, 0);
        }
    }
#pragma unroll
    for (int rt = 0; rt < 2; rt++) {
        int col = ct * 16 + l15;
#pragma unroll
        for (int rr = 0; rr < 4; rr++)
            z[(size_t)(e0 + rt * 16 + quad * 4 + rr) * MLc + col] = acc2[rt][rr];
    }
}

// node MLP with FUSED segment-max gather for the agg half of the input
__global__ __launch_bounds__(512) void k_node_mlp_mfma(
    float* __restrict__ g, const float* __restrict__ z,
    const int* __restrict__ rowstart, const int2* __restrict__ csr_se,
    const short* __restrict__ W1h, const short* __restrict__ W1l,
    const short* __restrict__ W2h, const short* __restrict__ W2l) {
    __shared__ short smem[2 * 32 * MS_N];        // 33792 B -> 4 blocks/CU, 32 waves
    short* m_hi = smem;
    short* m_lo = smem + 32 * MS_N;
    short* t_hi = smem;
    short* t_lo = smem + 32 * TS;
    const int tid = threadIdx.x;
    const int n0 = blockIdx.x * 32;

    for (int idx = tid; idx < 32 * 128; idx += 512) {
        int row = idx >> 7, pp = idx & 127, k = 2 * pp;
        float2 v;
        if (k < 128) {
            v = *(const float2*)&g[(size_t)(n0 + row) * MLc + k];
        } else {
            int n = n0 + row;
            int p0 = rowstart[n], p1 = rowstart[n + 1];
            int c = k - 128;
            float m0 = -3.0e38f, m1 = -3.0e38f;
            for (int p = p0; p < p1; p++) {
                const float* zr = &z[(size_t)csr_se[p].y * MLc + c];
                m0 = fmaxf(m0, zr[0]);
                m1 = fmaxf(m1, zr[1]);
            }
            v.x = (m0 > -1e30f) ? m0 : 0.0f;
            v.y = (m1 > -1e30f) ? m1 : 0.0f;
        }
        unsigned h0, l0, h1, l1;
        splitu(selu_f(v.x), h0, l0);
        splitu(selu_f(v.y), h1, l1);
        *(unsigned*)&m_hi[row * MS_N + k] = h0 | (h1 << 16);
        *(unsigned*)&m_lo[row * MS_N + k] = l0 | (l1 << 16);
    }
    __syncthreads();

    const int lane = tid & 63, ct = tid >> 6;
    const int l15 = lane & 15, quad = lane >> 4;

    f32x4 acc[2];
    acc[0] = (f32x4){0.f, 0.f, 0.f, 0.f};
    acc[1] = (f32x4){0.f, 0.f, 0.f, 0.f};
#pragma unroll 4
    for (int kc = 0; kc < 8; kc++) {
        size_t wo = (size_t)(ct * 16 + l15) * 256 + kc * 32 + quad * 8;
        short8 bh = *(const short8*)&W1h[wo];
        short8 bl = *(const short8*)&W1l[wo];
#pragma unroll
        for (int rt = 0; rt < 2; rt++) {
            const short* ap = &m_hi[(rt * 16 + l15) * MS_N + kc * 32 + quad * 8];
            short8 ah = *(const short8*)ap;
            short8 al = *(const short8*)(ap + 32 * MS_N);
            acc[rt] = __builtin_amdgcn_mfma_f32_16x16x32_bf16(ah, bh, acc[rt], 0, 0, 0);
            acc[rt] = __builtin_amdgcn_mfma_f32_16x16x32_bf16(al, bh, acc[rt], 0, 0, 0);
            acc[rt] = __builtin_amdgcn_mfma_f32_16x16x32_bf16(ah, bl, acc[rt], 0, 0, 0);
        }
    }
    __syncthreads();
#pragma unroll
    for (int rt = 0; rt < 2; rt++) {
        int col = ct * 16 + l15;
#pragma unroll
        for (int rr = 0; rr < 4; rr++) {
            unsigned h, l;
            splitu(selu_f(acc[rt][rr]), h, l);
            t_hi[(rt * 16 + quad * 4 + rr) * TS + col] = (short)h;
            t_lo[(rt * 16 + quad * 4 + rr) * TS + col] = (short)l;
        }
    }
    __syncthreads();

    f32x4 acc2[2];
    acc2[0] = (f32x4){0.f, 0.f, 0.f, 0.f};
    acc2[1] = (f32x4){0.f, 0.f, 0.f, 0.f};
#pragma unroll
    for (int kc = 0; kc < 4; kc++) {
        size_t wo = (size_t)(ct * 16 + l15) * 128 + kc * 32 + quad * 8;
        short8 bh = *(const short8*)&W2h[wo];
        short8 bl = *(const short8*)&W2l[wo];
#pragma unroll
        for (int rt = 0; rt < 2; rt++) {
            const short* ap = &t_hi[(rt * 16 + l15) * TS + kc * 32 + quad * 8];
            short8 ah = *(const short8*)ap;
            short8 al = *(const short8*)(ap + 32 * TS);
            acc2[rt] = __builtin_amdgcn_mfma_f32_16x16x32_bf16(ah, bh, acc2[rt], 0, 0, 0);
            acc2[rt] = __builtin_amdgcn_mfma_f32_16x16x32_bf16(al, bh, acc2[rt], 0, 0, 0);
            acc2[rt] = __builtin_amdgcn_mfma_f32_16x16x32_bf16(ah, bl, acc2[rt], 0, 0, 0);
        }
    }
#pragma unroll
    for (int rt = 0; rt < 2; rt++) {
        int col = ct * 16 + l15;
#pragma unroll
        for (int rr = 0; rr < 4; rr++)
            g[(size_t)(n0 + rt * 16 + quad * 4 + rr) * MLc + col] = acc2[rt][rr];
    }
}

// Wf chain on first-half edges: q_new = q_old + selu(selu(lam@Wf1)@Wf2)@Wf3; antisymmetrize.
__global__ __launch_bounds__(512) void k_wf_mfma(
    const float* __restrict__ g, const float* __restrict__ z,
    const short* __restrict__ W1h, const short* __restrict__ W1l,
    const short* __restrict__ W2h, const short* __restrict__ W2l,
    const float* __restrict__ W3 /*[128]*/,
    const int* __restrict__ sndr, const int* __restrict__ rcvr,
    float* __restrict__ qh) {
    __shared__ short smem[2 * 32 * MS_E];
    __shared__ float red[32 * 8];
    short* m_hi = smem;
    short* m_lo = smem + 32 * MS_E;
    short* t_hi = smem;
    short* t_lo = smem + 32 * TS;
    const int tid = threadIdx.x;
    const int fi0 = blockIdx.x * 32;
    const int b = fi0 / E2c;                  // block never straddles a batch (E2%32==0)
    const int ebase = b * EPGc - b * E2c;     // e = ebase + fi

    for (int idx = tid; idx < 32 * 192; idx += 512) {
        int row = idx / 192, pp = idx - row * 192, k = 2 * pp;
        int e = ebase + fi0 + row;
        float2 v;
        if (k < 128)       v = *(const float2*)&g[(size_t)sndr[e] * MLc + k];
        else if (k < 256)  v = *(const float2*)&g[(size_t)rcvr[e] * MLc + (k - 128)];
        else               v = *(const float2*)&z[(size_t)e * MLc + (k - 256)];
        unsigned h0, l0, h1, l1;
        splitu(selu_f(v.x), h0, l0);
        splitu(selu_f(v.y), h1, l1);
        *(unsigned*)&m_hi[row * MS_E + k] = h0 | (h1 << 16);
        *(unsigned*)&m_lo[row * MS_E + k] = l0 | (l1 << 16);
    }
    __syncthreads();

    const int lane = tid & 63, ct = tid >> 6;
    const int l15 = lane & 15, quad = lane >> 4;

    f32x4 acc[2];
    acc[0] = (f32x4){0.f, 0.f, 0.f, 0.f};
    acc[1] = (f32x4){0.f, 0.f, 0.f, 0.f};
#pragma unroll 4
    for (int kc = 0; kc < 12; kc++) {
        size_t wo = (size_t)(ct * 16 + l15) * 384 + kc * 32 + quad * 8;
        short8 bh = *(const short8*)&W1h[wo];
        short8 bl = *(const short8*)&W1l[wo];
#pragma unroll
        for (int rt = 0; rt < 2; rt++) {
            const short* ap = &m_hi[(rt * 16 + l15) * MS_E + kc * 32 + quad * 8];
            short8 ah = *(const short8*)ap;
            short8 al = *(const short8*)(ap + 32 * MS_E);
            acc[rt] = __builtin_amdgcn_mfma_f32_16x16x32_bf16(ah, bh, acc[rt], 0, 0, 0);
            acc[rt] = __builtin_amdgcn_mfma_f32_16x16x32_bf16(al, bh, acc[rt], 0, 0, 0);
            acc[rt] = __builtin_amdgcn_mfma_f32_16x16x32_bf16(ah, bl, acc[rt], 0, 0, 0);
        }
    }
    __syncthreads();
#pragma unroll
    for (int rt = 0; rt < 2; rt++) {
        int col = ct * 16 + l15;
#pragma unroll
        for (int rr = 0; rr < 4; rr++) {
            unsigned h, l;
            splitu(selu_f(acc[rt][rr]), h, l);
            t_hi[(rt * 16 + quad * 4 + rr) * TS + col] = (short)h;
            t_lo[(rt * 16 + quad * 4 + rr) * TS + col] = (short)l;
        }
    }
    __syncthreads();

    f32x4 acc2[2];
    acc2[0] = (f32x4){0.f, 0.f, 0.f, 0.f};
    acc2[1] = (f32x4){0.f, 0.f, 0.f, 0.f};
#pragma unroll
    for (int kc = 0; kc < 4; kc++) {
        size_t wo = (size_t)(ct * 16 + l15) * 128 + kc * 32 + quad * 8;
        short8 bh = *(const short8*)&W2h[wo];
        short8 bl = *(const short8*)&W2l[wo];
#pragma unroll
        for (int rt = 0; rt < 2; rt++) {
            const short* ap = &t_hi[(rt * 16 + l15) * TS + kc * 32 + quad * 8];
            short8 ah = *(const short8*)ap;
            short8 al = *(const short8*)(ap + 32 * TS);
            acc2[rt] = __builtin_amdgcn_mfma_f32_16x16x32_bf16(ah, bh, acc2[rt], 0, 0, 0);
            acc2[rt] = __builtin_amdgcn_mfma_f32_16x16x32_bf16(al, bh, acc2[rt], 0, 0, 0);
            acc2[rt] = __builtin_amdgcn_mfma_f32_16x16x32_bf16(ah, bl, acc2[rt], 0, 0, 0);
        }
    }
    // per-lane partial of sum_col selu(out[row][col]) * W3[col] over this wave's col-tile
    float w3 = W3[ct * 16 + l15];
    float p[8];
#pragma unroll
    for (int rt = 0; rt < 2; rt++)
#pragma unroll
        for (int rr = 0; rr < 4; rr++) p[rt * 4 + rr] = selu_f(acc2[rt][rr]) * w3;
    // reduce over the 16 cols (lane bits 0..3)
#pragma unroll
    for (int off = 1; off < 16; off <<= 1) {
#pragma unroll
        for (int i = 0; i < 8; i++) p[i] += __shfl_xor(p[i], off, 64);
    }
    if (l15 == 0) {
#pragma unroll
        for (int rt = 0; rt < 2; rt++)
#pragma unroll
            for (int rr = 0; rr < 4; rr++)
                red[(rt * 16 + quad * 4 + rr) * 8 + ct] = p[rt * 4 + rr];
    }
    __syncthreads();
    if (tid < 32) {
        float f = 0.0f;
#pragma unroll
        for (int c = 0; c < 8; c++) f += red[tid * 8 + c];
        int e = ebase + fi0 + tid;
        float qn = qh[e] + f;
        qh[e] = qn;
        qh[e + E2c] = -qn;
    }
}

// ---------------- host orchestration ----------------

extern "C" void kernel_launch(void* const* d_in, const int* in_sizes, int n_in,
                              void* d_out, int out_size, void* d_ws, size_t ws_size,
                              hipStream_t stream) {
    const float* x   = (const float*)d_in[0];
    const float* r   = (const float*)d_in[1];
    const float* Wni = (const float*)d_in[2];
    const float* Wei = (const float*)d_in[3];
    const float* Wf1 = (const float*)d_in[4];
    const float* Wf2 = (const float*)d_in[5];
    const float* Wf3 = (const float*)d_in[6];
    const float* We1 = (const float*)d_in[7];   // (3,384,128)
    const float* We2 = (const float*)d_in[8];   // (3,128,128)
    const float* Wn1 = (const float*)d_in[9];   // (3,256,128)
    const float* Wn2 = (const float*)d_in[10];  // (3,128,128)
    const int* sndr  = (const int*)d_in[11];
    const int* rcvr  = (const int*)d_in[12];
    float* out = (float*)d_out;

    char* wp = (char*)d_ws;
    auto carve = [&](size_t bytes) -> void* {
        void* ret = (void*)wp;
        wp += (bytes + 255) & ~(size_t)255;
        return ret;
    };
    float* g      = (float*)carve((size_t)NNc * MLc * 4);
    float* z      = (float*)carve((size_t)NEc * MLc * 4);
    float* qh     = (float*)carve((size_t)NEc * 4);
    float* qt     = (float*)carve((size_t)NEc * 4);
    float* dh     = (float*)carve((size_t)NNc * 4);
    float* hl     = (float*)carve((size_t)NEc * 4);
    float* hA     = (float*)carve((size_t)NNc * 4);
    float* hB     = (float*)carve((size_t)NNc * 4);
    int*   deg    = (int*)carve((size_t)NNc * 4);
    int*   cursor = (int*)carve((size_t)NNc * 4);
    int*   rowst  = (int*)carve((size_t)(NNc + 1) * 4);
    int2*  csr_se = (int2*)carve((size_t)NEc * 8);
    short* we1h   = (short*)carve((size_t)3 * 128 * 384 * 2);
    short* we1l   = (short*)carve((size_t)3 * 128 * 384 * 2);
    short* we2h   = (short*)carve((size_t)3 * 128 * 128 * 2);
    short* we2l   = (short*)carve((size_t)3 * 128 * 128 * 2);
    short* wn1h   = (short*)carve((size_t)3 * 128 * 256 * 2);
    short* wn1l   = (short*)carve((size_t)3 * 128 * 256 * 2);
    short* wn2h   = (short*)carve((size_t)3 * 128 * 128 * 2);
    short* wn2l   = (short*)carve((size_t)3 * 128 * 128 * 2);
    short* wf1h   = (short*)carve((size_t)128 * 384 * 2);
    short* wf1l   = (short*)carve((size_t)128 * 384 * 2);
    short* wf2h   = (short*)carve((size_t)128 * 128 * 2);
    short* wf2l   = (short*)carve((size_t)128 * 128 * 2);

    const int TB = 256;
    const int gN  = (NNc + TB - 1) / TB;
    const int gE  = (NEc + TB - 1) / TB;
    const int gNM = NNc * MLc / TB;

    // weight bf16 hi/lo transposed copies
    for (int i = 0; i < 3; i++) {
        k_wconv2<<<(128 * 384 + 255) / 256, TB, 0, stream>>>(We1 + (size_t)i * 384 * 128, we1h + (size_t)i * 128 * 384, we1l + (size_t)i * 128 * 384, 384);
        k_wconv2<<<(128 * 128 + 255) / 256, TB, 0, stream>>>(We2 + (size_t)i * 128 * 128, we2h + (size_t)i * 128 * 128, we2l + (size_t)i * 128 * 128, 128);
        k_wconv2<<<(128 * 256 + 255) / 256, TB, 0, stream>>>(Wn1 + (size_t)i * 256 * 128, wn1h + (size_t)i * 128 * 256, wn1l + (size_t)i * 128 * 256, 256);
        k_wconv2<<<(128 * 128 + 255) / 256, TB, 0, stream>>>(Wn2 + (size_t)i * 128 * 128, wn2h + (size_t)i * 128 * 128, wn2l + (size_t)i * 128 * 128, 128);
    }
    k_wconv2<<<(128 * 384 + 255) / 256, TB, 0, stream>>>(Wf1, wf1h, wf1l, 384);
    k_wconv2<<<(128 * 128 + 255) / 256, TB, 0, stream>>>(Wf2, wf2h, wf2l, 128);

    // CSR build
    k_zero_i<<<gN, TB, 0, stream>>>(deg, NNc);
    k_count<<<gE, TB, 0, stream>>>(rcvr, deg);
    k_scan<<<1, TB, 0, stream>>>(deg, rowst, cursor);
    k_scatter<<<gE, TB, 0, stream>>>(sndr, rcvr, cursor, csr_se);

    // initial flows
    k_qinit<<<gE, TB, 0, stream>>>(x, r, sndr, rcvr, qh, qt);
    k_segsum_csr<<<gN, TB, 0, stream>>>(qh, rowst, csr_se, dh);

    float* hcur = hA;
    float* hnxt = hB;
    for (int kit = 0; kit < 4; kit++) {
        k_node_in<<<gNM, TB, 0, stream>>>(dh, x, Wni, g);
        k_edge_in<<<NEc * MLc / TB, TB, 0, stream>>>(qt, qh, Wei, z);
        for (int i = 0; i < 3; i++) {
            k_edge_mlp_mfma<<<NEc / 32, 512, 0, stream>>>(g, z,
                we1h + (size_t)i * 128 * 384, we1l + (size_t)i * 128 * 384,
                we2h + (size_t)i * 128 * 128, we2l + (size_t)i * 128 * 128, sndr, rcvr);
            k_node_mlp_mfma<<<NNc / 32, 512, 0, stream>>>(g, z, rowst, csr_se,
                wn1h + (size_t)i * 128 * 256, wn1l + (size_t)i * 128 * 256,
                wn2h + (size_t)i * 128 * 128, wn2l + (size_t)i * 128 * 128);
        }
        k_wf_mfma<<<(4 * E2c) / 32, 512, 0, stream>>>(g, z, wf1h, wf1l, wf2h, wf2l,
                                                      Wf3, sndr, rcvr, qh);
        k_segsum_csr<<<gN, TB, 0, stream>>>(qh, rowst, csr_se, dh);
        // heads
        k_hl<<<gE, TB, 0, stream>>>(qh, r, hl);
        k_copy_h<<<gN, TB, 0, stream>>>(x, hcur);
        for (int jh = 0; jh < 6; jh++) {
            k_head_iter<<<gN, TB, 0, stream>>>(x, hcur, hl, rowst, csr_se, hnxt);
            float* tmp = hcur; hcur = hnxt; hnxt = tmp;
        }
        k_flows_q<<<gE, TB, 0, stream>>>(hcur, r, sndr, rcvr, qt);
    }
    k_out<<<gN, TB, 0, stream>>>(hcur, out);
}

// Round 5
// 3466.192 us; speedup vs baseline: 2.2529x; 1.0342x over previous
//
#include <hip/hip_runtime.h>
#include <hip/hip_bf16.h>
#include <math.h>

// Problem constants
#define NPGc  10000
#define EPGc  32000
#define MLc   128
#define NNc   40000      // N
#define NEc   128000     // E
#define E2c   16000      // EPG/2
#define ZETAc 1e-6f
#define INVPc 0.53995680345572354f   // 1/1.852
#define PEXPc 1.852f

typedef __attribute__((ext_vector_type(8))) short short8;   // 8 bf16 (4 VGPRs)
typedef __attribute__((ext_vector_type(4))) float f32x4;    // MFMA acc

// fast selu: __expf -> v_exp_f32
__device__ __forceinline__ float selu_f(float x) {
    float e = __expf(x) - 1.0f;
    return 1.0507009873554805f * (x > 0.0f ? x : 1.6732632423543772f * e);
}
// split fp32 -> (hi, lo) bf16 pair: v ~= hi + lo, residual ~2^-18 relative
__device__ __forceinline__ void splitu(float v, unsigned& hi, unsigned& lo) {
    __hip_bfloat16 h = __float2bfloat16(v);
    hi = (unsigned short)*reinterpret_cast<short*>(&h);
    float rem = v - __bfloat162float(h);
    __hip_bfloat16 l = __float2bfloat16(rem);
    lo = (unsigned short)*reinterpret_cast<short*>(&l);
}
__device__ __forceinline__ float signf(float x) {
    return (x > 0.0f) ? 1.0f : (x < 0.0f ? -1.0f : 0.0f);
}

// ---------------- weight convert+transpose+split: dst[n][k] = split(src[k][n]) ----------------
__global__ void k_wconv2(const float* __restrict__ src, short* __restrict__ dh,
                         short* __restrict__ dl, int K) {
    int gid = blockIdx.x * 256 + threadIdx.x;
    if (gid >= 128 * K) return;
    int n = gid / K, k = gid - n * K;
    unsigned h, l;
    splitu(src[k * 128 + n], h, l);
    dh[n * K + k] = (short)h;
    dl[n * K + k] = (short)l;
}

// ---------------- CSR build (by rcvr) ----------------
__global__ void k_zero_i(int* p, int n) {
    int i = blockIdx.x * 256 + threadIdx.x;
    if (i < n) p[i] = 0;
}
__global__ void k_count(const int* __restrict__ rcvr, int* __restrict__ deg) {
    int e = blockIdx.x * 256 + threadIdx.x;
    if (e < NEc) atomicAdd(&deg[rcvr[e]], 1);
}
__global__ void k_scan(const int* __restrict__ deg, int* __restrict__ rowstart,
                       int* __restrict__ cursor) {
    __shared__ int sums[256];
    const int tid = threadIdx.x;
    const int CH = (NNc + 255) / 256;
    const int i0 = tid * CH;
    int s = 0;
    for (int j = 0; j < CH; j++) {
        int i = i0 + j;
        if (i < NNc) s += deg[i];
    }
    sums[tid] = s;
    __syncthreads();
    for (int off = 1; off < 256; off <<= 1) {
        int t = (tid >= off) ? sums[tid - off] : 0;
        __syncthreads();
        sums[tid] += t;
        __syncthreads();
    }
    int base = sums[tid] - s;
    for (int j = 0; j < CH; j++) {
        int i = i0 + j;
        if (i < NNc) {
            rowstart[i] = base;
            cursor[i] = base;
            base += deg[i];
        }
    }
    if (tid == 255) rowstart[NNc] = base;
}
__global__ void k_scatter(const int* __restrict__ sndr, const int* __restrict__ rcvr,
                          int* __restrict__ cursor, int2* __restrict__ csr_se) {
    int e = blockIdx.x * 256 + threadIdx.x;
    if (e >= NEc) return;
    int rv = rcvr[e];
    int p = atomicAdd(&cursor[rv], 1);
    csr_se[p] = make_int2(sndr[e], e);
}

// ---------------- flows / elementwise ----------------
__global__ void k_qinit(const float* __restrict__ x, const float* __restrict__ r,
                        const int* __restrict__ sndr, const int* __restrict__ rcvr,
                        float* __restrict__ qh, float* __restrict__ qt) {
    int e = blockIdx.x * 256 + threadIdx.x;
    if (e >= NEc) return;
    float hv = x[2 * sndr[e]] - x[2 * rcvr[e]];
    float q = signf(hv) * __powf((fabsf(hv) + ZETAc) / (r[e] + ZETAc), INVPc);
    qh[e] = q; qt[e] = q;
}
__global__ void k_flows_q(const float* __restrict__ h, const float* __restrict__ r,
                          const int* __restrict__ sndr, const int* __restrict__ rcvr,
                          float* __restrict__ qt) {
    int e = blockIdx.x * 256 + threadIdx.x;
    if (e >= NEc) return;
    float hv = h[sndr[e]] - h[rcvr[e]];
    qt[e] = signf(hv) * __powf((fabsf(hv) + ZETAc) / (r[e] + ZETAc), INVPc);
}

// node-in, fused segsum: one WAVE per node. Produces split-selu g planes.
__global__ __launch_bounds__(256) void k_node_in_f(
    const float* __restrict__ qh, const int* __restrict__ rowstart,
    const int2* __restrict__ csr_se, const float* __restrict__ x,
    const float* __restrict__ W /*2x128*/,
    unsigned* __restrict__ gh_u, unsigned* __restrict__ gl_u) {
    const int tid = threadIdx.x;
    const int lane = tid & 63;
    const int n = blockIdx.x * 4 + (tid >> 6);
    if (n >= NNc) return;
    int p0 = rowstart[n], p1 = rowstart[n + 1];
    float s = 0.0f;
    for (int p = p0 + lane; p < p1; p += 64) s += qh[csr_se[p].y];
#pragma unroll
    for (int off = 1; off < 64; off <<= 1) s += __shfl_xor(s, off, 64);
    float s0 = selu_f(s);
    float s1 = selu_f(x[2 * n + 1]);
    int c = lane * 2;
    float g0 = s0 * W[c]     + s1 * W[MLc + c];
    float g1 = s0 * W[c + 1] + s1 * W[MLc + c + 1];
    unsigned h0, l0, h1, l1;
    splitu(selu_f(g0), h0, l0);
    splitu(selu_f(g1), h1, l1);
    gh_u[(size_t)n * 64 + lane] = h0 | (h1 << 16);
    gl_u[(size_t)n * 64 + lane] = l0 | (l1 << 16);
}

// hl + copy_h fused
__global__ void k_hl_copy(const float* __restrict__ qh, const float* __restrict__ r,
                          const float* __restrict__ x,
                          float* __restrict__ hl, float* __restrict__ h) {
    int i = blockIdx.x * 256 + threadIdx.x;
    if (i < NEc) {
        float q = qh[i];
        hl[i] = r[i] * signf(q) * __powf(fabsf(q), PEXPc);
    }
    if (i < NNc) h[i] = x[2 * i];
}
// one head-propagation iteration, CSR gather, ping-pong
__global__ void k_head_iter(const float* __restrict__ x, const float* __restrict__ hin,
                            const float* __restrict__ hl, const int* __restrict__ rowstart,
                            const int2* __restrict__ csr_se, float* __restrict__ hout) {
    int n = blockIdx.x * 256 + threadIdx.x;
    if (n >= NNc) return;
    float hv = hin[n];
    float m = -3.0e38f;
    int p0 = rowstart[n], p1 = rowstart[n + 1];
    for (int p = p0; p < p1; p++) {
        int2 se = csr_se[p];
        m = fmaxf(m, hin[se.x] - hl[se.y]);
    }
    float a = (m > -1e30f) ? m : hv;
    float hstar = x[2 * n];
    hout[n] = (hstar != 0.0f) ? hstar : fmaxf(hv, a);
}

// ---------------- split-bf16 MFMA MLP kernels ----------------
// Inputs arrive as pre-split selu planes (h/l shorts, 2 cols packed per dword).
// 32-row tile, 512 threads = 8 waves; wave = 16-col tile x both 16-row tiles.
// A-frag: row=lane&15, k=quad*8+j. C/D: col=lane&15, row=quad*4+reg.

#define MS_E 392   // 384+8 shorts
#define MS_N 264   // 256+8
#define TS   136   // 128+8

// epilogue pack helper: lane parity selects hi/lo plane dword
__device__ __forceinline__ void pack_pair(unsigned h, unsigned l, bool ev,
                                          unsigned& word) {
    unsigned oh = __shfl_xor((int)h, 1, 64);
    unsigned ol = __shfl_xor((int)l, 1, 64);
    unsigned wh = ev ? (h | (oh << 16)) : (oh | (h << 16));
    unsigned wl = ev ? (l | (ol << 16)) : (ol | (l << 16));
    word = ev ? wh : wl;
}

__global__ __launch_bounds__(512) void k_edge_mlp_mfma(
    const unsigned* __restrict__ gh_u, const unsigned* __restrict__ gl_u,
    const unsigned* __restrict__ zh_u, const unsigned* __restrict__ zl_u,
    unsigned* __restrict__ zoh_u, unsigned* __restrict__ zol_u,
    const short* __restrict__ W1h, const short* __restrict__ W1l,
    const short* __restrict__ W2h, const short* __restrict__ W2l,
    const int* __restrict__ sndr, const int* __restrict__ rcvr,
    const float* __restrict__ qt, const float* __restrict__ qh,
    const float* __restrict__ Wei, int zmode) {
    __shared__ short smem[2 * 32 * MS_E];        // 50176 B
    short* m_hi = smem;
    short* m_lo = smem + 32 * MS_E;
    short* t_hi = smem;                          // alias front (post-barrier)
    short* t_lo = smem + 32 * TS;
    const int tid = threadIdx.x;
    const int e0 = blockIdx.x * 32;

    for (int idx = tid; idx < 32 * 192; idx += 512) {
        int row = idx / 192, pp = idx - row * 192;
        int region = pp >> 6, cp = pp & 63;
        int e = e0 + row;
        unsigned uh, ul;
        if (region == 0) {
            size_t o = (size_t)sndr[e] * 64 + cp;
            uh = gh_u[o]; ul = gl_u[o];
        } else if (region == 1) {
            size_t o = (size_t)rcvr[e] * 64 + cp;
            uh = gh_u[o]; ul = gl_u[o];
        } else if (zmode == 0) {
            size_t o = (size_t)e * 64 + cp;
            uh = zh_u[o]; ul = zl_u[o];
        } else {
            float sqt = selu_f(qt[e]), sqh = selu_f(qh[e]);
            int c = 2 * cp;
            float z0 = sqt * Wei[c]     + sqh * Wei[MLc + c];
            float z1 = sqt * Wei[c + 1] + sqh * Wei[MLc + c + 1];
            unsigned h0, l0, h1, l1;
            splitu(selu_f(z0), h0, l0);
            splitu(selu_f(z1), h1, l1);
            uh = h0 | (h1 << 16); ul = l0 | (l1 << 16);
        }
        int k = region * 128 + 2 * cp;
        *(unsigned*)&m_hi[row * MS_E + k] = uh;
        *(unsigned*)&m_lo[row * MS_E + k] = ul;
    }
    __syncthreads();

    const int lane = tid & 63, ct = tid >> 6;
    const int l15 = lane & 15, quad = lane >> 4;
    const bool ev = (l15 & 1) == 0;
    const int col = ct * 16 + l15;

    f32x4 acc[2];
    acc[0] = (f32x4){0.f, 0.f, 0.f, 0.f};
    acc[1] = (f32x4){0.f, 0.f, 0.f, 0.f};
#pragma unroll 4
    for (int kc = 0; kc < 12; kc++) {
        size_t wo = (size_t)col * 384 + kc * 32 + quad * 8;
        short8 bh = *(const short8*)&W1h[wo];
        short8 bl = *(const short8*)&W1l[wo];
#pragma unroll
        for (int rt = 0; rt < 2; rt++) {
            const short* ap = &m_hi[(rt * 16 + l15) * MS_E + kc * 32 + quad * 8];
            short8 ah = *(const short8*)ap;
            short8 al = *(const short8*)(ap + 32 * MS_E);
            acc[rt] = __builtin_amdgcn_mfma_f32_16x16x32_bf16(ah, bh, acc[rt], 0, 0, 0);
            acc[rt] = __builtin_amdgcn_mfma_f32_16x16x32_bf16(al, bh, acc[rt], 0, 0, 0);
            acc[rt] = __builtin_amdgcn_mfma_f32_16x16x32_bf16(ah, bl, acc[rt], 0, 0, 0);
        }
    }
    __syncthreads();
#pragma unroll
    for (int rt = 0; rt < 2; rt++) {
#pragma unroll
        for (int rr = 0; rr < 4; rr++) {
            unsigned h, l, word;
            splitu(selu_f(acc[rt][rr]), h, l);
            pack_pair(h, l, ev, word);
            short* basep = ev ? t_hi : t_lo;
            *(unsigned*)&basep[(rt * 16 + quad * 4 + rr) * TS + (col & ~1)] = word;
        }
    }
    __syncthreads();

    f32x4 acc2[2];
    acc2[0] = (f32x4){0.f, 0.f, 0.f, 0.f};
    acc2[1] = (f32x4){0.f, 0.f, 0.f, 0.f};
#pragma unroll
    for (int kc = 0; kc < 4; kc++) {
        size_t wo = (size_t)col * 128 + kc * 32 + quad * 8;
        short8 bh = *(const short8*)&W2h[wo];
        short8 bl = *(const short8*)&W2l[wo];
#pragma unroll
        for (int rt = 0; rt < 2; rt++) {
            const short* ap = &t_hi[(rt * 16 + l15) * TS + kc * 32 + quad * 8];
            short8 ah = *(const short8*)ap;
            short8 al = *(const short8*)(ap + 32 * TS);
            acc2[rt] = __builtin_amdgcn_mfma_f32_16x16x32_bf16(ah, bh, acc2[rt], 0, 0, 0);
            acc2[rt] = __builtin_amdgcn_mfma_f32_16x16x32_bf16(al, bh, acc2[rt], 0, 0, 0);
            acc2[rt] = __builtin_amdgcn_mfma_f32_16x16x32_bf16(ah, bl, acc2[rt], 0, 0, 0);
        }
    }
    // write z output planes: split(selu(z_raw)) packed
#pragma unroll
    for (int rt = 0; rt < 2; rt++) {
#pragma unroll
        for (int rr = 0; rr < 4; rr++) {
            unsigned h, l, word;
            splitu(selu_f(acc2[rt][rr]), h, l);
            pack_pair(h, l, ev, word);
            unsigned* plane = ev ? zoh_u : zol_u;
            plane[(size_t)(e0 + rt * 16 + quad * 4 + rr) * 64 + (col >> 1)] = word;
        }
    }
}

// node MLP: staging gathers g planes + selu-space segment max of z planes
__global__ __launch_bounds__(512) void k_node_mlp_mfma(
    const unsigned* __restrict__ gh_u, const unsigned* __restrict__ gl_u,
    unsigned* __restrict__ goh_u, unsigned* __restrict__ gol_u,
    const unsigned* __restrict__ zh_u, const unsigned* __restrict__ zl_u,
    const int* __restrict__ rowstart, const int2* __restrict__ csr_se,
    const short* __restrict__ W1h, const short* __restrict__ W1l,
    const short* __restrict__ W2h, const short* __restrict__ W2l) {
    __shared__ short smem[2 * 32 * MS_N];        // 33792 B
    short* m_hi = smem;
    short* m_lo = smem + 32 * MS_N;
    short* t_hi = smem;
    short* t_lo = smem + 32 * TS;
    const int tid = threadIdx.x;
    const int n0 = blockIdx.x * 32;

    for (int idx = tid; idx < 32 * 128; idx += 512) {
        int row = idx >> 7, pp = idx & 127;
        int region = pp >> 6, cp = pp & 63;
        int n = n0 + row;
        unsigned uh, ul;
        if (region == 0) {
            size_t o = (size_t)n * 64 + cp;
            uh = gh_u[o]; ul = gl_u[o];
        } else {
            // segment max in selu space over CSR edges (selu monotone)
            int p0 = rowstart[n], p1 = rowstart[n + 1];
            float b0 = -3.0e38f, b1 = -3.0e38f;
            unsigned bh0 = 0, bl0 = 0, bh1 = 0, bl1 = 0;  // default split(0)
            for (int p = p0; p < p1; p++) {
                size_t o = (size_t)csr_se[p].y * 64 + cp;
                unsigned vh = zh_u[o], vl = zl_u[o];
                float f0 = __uint_as_float(vh << 16) + __uint_as_float(vl << 16);
                float f1 = __uint_as_float(vh & 0xffff0000u) + __uint_as_float(vl & 0xffff0000u);
                if (f0 > b0) { b0 = f0; bh0 = vh & 0xffffu; bl0 = vl & 0xffffu; }
                if (f1 > b1) { b1 = f1; bh1 = vh & 0xffff0000u; bl1 = vl & 0xffff0000u; }
            }
            uh = bh0 | bh1; ul = bl0 | bl1;
        }
        int k = region * 128 + 2 * cp;
        *(unsigned*)&m_hi[row * MS_N + k] = uh;
        *(unsigned*)&m_lo[row * MS_N + k] = ul;
    }
    __syncthreads();

    const int lane = tid & 63, ct = tid >> 6;
    const int l15 = lane & 15, quad = lane >> 4;
    const bool ev = (l15 & 1) == 0;
    const int col = ct * 16 + l15;

    f32x4 acc[2];
    acc[0] = (f32x4){0.f, 0.f, 0.f, 0.f};
    acc[1] = (f32x4){0.f, 0.f, 0.f, 0.f};
#pragma unroll 4
    for (int kc = 0; kc < 8; kc++) {
        size_t wo = (size_t)col * 256 + kc * 32 + quad * 8;
        short8 bh = *(const short8*)&W1h[wo];
        short8 bl = *(const short8*)&W1l[wo];
#pragma unroll
        for (int rt = 0; rt < 2; rt++) {
            const short* ap = &m_hi[(rt * 16 + l15) * MS_N + kc * 32 + quad * 8];
            short8 ah = *(const short8*)ap;
            short8 al = *(const short8*)(ap + 32 * MS_N);
            acc[rt] = __builtin_amdgcn_mfma_f32_16x16x32_bf16(ah, bh, acc[rt], 0, 0, 0);
            acc[rt] = __builtin_amdgcn_mfma_f32_16x16x32_bf16(al, bh, acc[rt], 0, 0, 0);
            acc[rt] = __builtin_amdgcn_mfma_f32_16x16x32_bf16(ah, bl, acc[rt], 0, 0, 0);
        }
    }
    __syncthreads();
#pragma unroll
    for (int rt = 0; rt < 2; rt++) {
#pragma unroll
        for (int rr = 0; rr < 4; rr++) {
            unsigned h, l, word;
            splitu(selu_f(acc[rt][rr]), h, l);
            pack_pair(h, l, ev, word);
            short* basep = ev ? t_hi : t_lo;
            *(unsigned*)&basep[(rt * 16 + quad * 4 + rr) * TS + (col & ~1)] = word;
        }
    }
    __syncthreads();

    f32x4 acc2[2];
    acc2[0] = (f32x4){0.f, 0.f, 0.f, 0.f};
    acc2[1] = (f32x4){0.f, 0.f, 0.f, 0.f};
#pragma unroll
    for (int kc = 0; kc < 4; kc++) {
        size_t wo = (size_t)col * 128 + kc * 32 + quad * 8;
        short8 bh = *(const short8*)&W2h[wo];
        short8 bl = *(const short8*)&W2l[wo];
#pragma unroll
        for (int rt = 0; rt < 2; rt++) {
            const short* ap = &t_hi[(rt * 16 + l15) * TS + kc * 32 + quad * 8];
            short8 ah = *(const short8*)ap;
            short8 al = *(const short8*)(ap + 32 * TS);
            acc2[rt] = __builtin_amdgcn_mfma_f32_16x16x32_bf16(ah, bh, acc2[rt], 0, 0, 0);
            acc2[rt] = __builtin_amdgcn_mfma_f32_16x16x32_bf16(al, bh, acc2[rt], 0, 0, 0);
            acc2[rt] = __builtin_amdgcn_mfma_f32_16x16x32_bf16(ah, bl, acc2[rt], 0, 0, 0);
        }
    }
#pragma unroll
    for (int rt = 0; rt < 2; rt++) {
#pragma unroll
        for (int rr = 0; rr < 4; rr++) {
            unsigned h, l, word;
            splitu(selu_f(acc2[rt][rr]), h, l);
            pack_pair(h, l, ev, word);
            unsigned* plane = ev ? goh_u : gol_u;
            plane[(size_t)(n0 + rt * 16 + quad * 4 + rr) * 64 + (col >> 1)] = word;
        }
    }
}

// Wf chain on first-half edges: q_new = q_old + selu(selu(lam@Wf1)@Wf2)@Wf3; antisymmetrize.
__global__ __launch_bounds__(512) void k_wf_mfma(
    const unsigned* __restrict__ gh_u, const unsigned* __restrict__ gl_u,
    const unsigned* __restrict__ zh_u, const unsigned* __restrict__ zl_u,
    const short* __restrict__ W1h, const short* __restrict__ W1l,
    const short* __restrict__ W2h, const short* __restrict__ W2l,
    const float* __restrict__ W3 /*[128]*/,
    const int* __restrict__ sndr, const int* __restrict__ rcvr,
    float* __restrict__ qh) {
    __shared__ short smem[2 * 32 * MS_E];
    __shared__ float red[32 * 8];
    short* m_hi = smem;
    short* m_lo = smem + 32 * MS_E;
    short* t_hi = smem;
    short* t_lo = smem + 32 * TS;
    const int tid = threadIdx.x;
    const int fi0 = blockIdx.x * 32;
    const int b = fi0 / E2c;
    const int ebase = b * EPGc - b * E2c;     // e = ebase + fi

    for (int idx = tid; idx < 32 * 192; idx += 512) {
        int row = idx / 192, pp = idx - row * 192;
        int region = pp >> 6, cp = pp & 63;
        int e = ebase + fi0 + row;
        size_t o;
        const unsigned *ph, *pl;
        if (region == 0)      { o = (size_t)sndr[e] * 64 + cp; ph = gh_u; pl = gl_u; }
        else if (region == 1) { o = (size_t)rcvr[e] * 64 + cp; ph = gh_u; pl = gl_u; }
        else                  { o = (size_t)e * 64 + cp;       ph = zh_u; pl = zl_u; }
        int k = region * 128 + 2 * cp;
        *(unsigned*)&m_hi[row * MS_E + k] = ph[o];
        *(unsigned*)&m_lo[row * MS_E + k] = pl[o];
    }
    __syncthreads();

    const int lane = tid & 63, ct = tid >> 6;
    const int l15 = lane & 15, quad = lane >> 4;
    const bool ev = (l15 & 1) == 0;
    const int col = ct * 16 + l15;

    f32x4 acc[2];
    acc[0] = (f32x4){0.f, 0.f, 0.f, 0.f};
    acc[1] = (f32x4){0.f, 0.f, 0.f, 0.f};
#pragma unroll 4
    for (int kc = 0; kc < 12; kc++) {
        size_t wo = (size_t)col * 384 + kc * 32 + quad * 8;
        short8 bh = *(const short8*)&W1h[wo];
        short8 bl = *(const short8*)&W1l[wo];
#pragma unroll
        for (int rt = 0; rt < 2; rt++) {
            const short* ap = &m_hi[(rt * 16 + l15) * MS_E + kc * 32 + quad * 8];
            short8 ah = *(const short8*)ap;
            short8 al = *(const short8*)(ap + 32 * MS_E);
            acc[rt] = __builtin_amdgcn_mfma_f32_16x16x32_bf16(ah, bh, acc[rt], 0, 0, 0);
            acc[rt] = __builtin_amdgcn_mfma_f32_16x16x32_bf16(al, bh, acc[rt], 0, 0, 0);
            acc[rt] = __builtin_amdgcn_mfma_f32_16x16x32_bf16(ah, bl, acc[rt], 0, 0, 0);
        }
    }
    __syncthreads();
#pragma unroll
    for (int rt = 0; rt < 2; rt++) {
#pragma unroll
        for (int rr = 0; rr < 4; rr++) {
            unsigned h, l, word;
            splitu(selu_f(acc[rt][rr]), h, l);
            pack_pair(h, l, ev, word);
            short* basep = ev ? t_hi : t_lo;
            *(unsigned*)&basep[(rt * 16 + quad * 4 + rr) * TS + (col & ~1)] = word;
        }
    }
    __syncthreads();

    f32x4 acc2[2];
    acc2[0] = (f32x4){0.f, 0.f, 0.f, 0.f};
    acc2[1] = (f32x4){0.f, 0.f, 0.f, 0.f};
#pragma unroll
    for (int kc = 0; kc < 4; kc++) {
        size_t wo = (size_t)col * 128 + kc * 32 + quad * 8;
        short8 bh = *(const short8*)&W2h[wo];
        short8 bl = *(const short8*)&W2l[wo];
#pragma unroll
        for (int rt = 0; rt < 2; rt++) {
            const short* ap = &t_hi[(rt * 16 + l15) * TS + kc * 32 + quad * 8];
            short8 ah = *(const short8*)ap;
            short8 al = *(const short8*)(ap + 32 * TS);
            acc2[rt] = __builtin_amdgcn_mfma_f32_16x16x32_bf16(ah, bh, acc2[rt], 0, 0, 0);
            acc2[rt] = __builtin_amdgcn_mfma_f32_16x16x32_bf16(al, bh, acc2[rt], 0, 0, 0);
            acc2[rt] = __builtin_amdgcn_mfma_f32_16x16x32_bf16(ah, bl, acc2[rt], 0, 0, 0);
        }
    }
    float w3 = W3[col];
    float p[8];
#pragma unroll
    for (int rt = 0; rt < 2; rt++)
#pragma unroll
        for (int rr = 0; rr < 4; rr++) p[rt * 4 + rr] = selu_f(acc2[rt][rr]) * w3;
#pragma unroll
    for (int off = 1; off < 16; off <<= 1) {
#pragma unroll
        for (int i = 0; i < 8; i++) p[i] += __shfl_xor(p[i], off, 64);
    }
    if (l15 == 0) {
#pragma unroll
        for (int rt = 0; rt < 2; rt++)
#pragma unroll
            for (int rr = 0; rr < 4; rr++)
                red[(rt * 16 + quad * 4 + rr) * 8 + ct] = p[rt * 4 + rr];
    }
    __syncthreads();
    if (tid < 32) {
        float f = 0.0f;
#pragma unroll
        for (int c = 0; c < 8; c++) f += red[tid * 8 + c];
        int e = ebase + fi0 + tid;
        float qn = qh[e] + f;
        qh[e] = qn;
        qh[e + E2c] = -qn;
    }
}

// ---------------- host orchestration ----------------

extern "C" void kernel_launch(void* const* d_in, const int* in_sizes, int n_in,
                              void* d_out, int out_size, void* d_ws, size_t ws_size,
                              hipStream_t stream) {
    const float* x   = (const float*)d_in[0];
    const float* r   = (const float*)d_in[1];
    const float* Wni = (const float*)d_in[2];
    const float* Wei = (const float*)d_in[3];
    const float* Wf1 = (const float*)d_in[4];
    const float* Wf2 = (const float*)d_in[5];
    const float* Wf3 = (const float*)d_in[6];
    const float* We1 = (const float*)d_in[7];   // (3,384,128)
    const float* We2 = (const float*)d_in[8];   // (3,128,128)
    const float* Wn1 = (const float*)d_in[9];   // (3,256,128)
    const float* Wn2 = (const float*)d_in[10];  // (3,128,128)
    const int* sndr  = (const int*)d_in[11];
    const int* rcvr  = (const int*)d_in[12];
    float* out = (float*)d_out;

    char* wp = (char*)d_ws;
    auto carve = [&](size_t bytes) -> void* {
        void* ret = (void*)wp;
        wp += (bytes + 255) & ~(size_t)255;
        return ret;
    };
    unsigned* gh_u = (unsigned*)carve((size_t)NNc * 64 * 4);
    unsigned* gl_u = (unsigned*)carve((size_t)NNc * 64 * 4);
    unsigned* zAh  = (unsigned*)carve((size_t)NEc * 64 * 4);
    unsigned* zAl  = (unsigned*)carve((size_t)NEc * 64 * 4);
    unsigned* zBh  = (unsigned*)carve((size_t)NEc * 64 * 4);
    unsigned* zBl  = (unsigned*)carve((size_t)NEc * 64 * 4);
    float* qh     = (float*)carve((size_t)NEc * 4);
    float* qt     = (float*)carve((size_t)NEc * 4);
    float* hl     = (float*)carve((size_t)NEc * 4);
    float* hA     = (float*)carve((size_t)NNc * 4);
    float* hB     = (float*)carve((size_t)NNc * 4);
    int*   deg    = (int*)carve((size_t)NNc * 4);
    int*   cursor = (int*)carve((size_t)NNc * 4);
    int*   rowst  = (int*)carve((size_t)(NNc + 1) * 4);
    int2*  csr_se = (int2*)carve((size_t)NEc * 8);
    short* we1h   = (short*)carve((size_t)3 * 128 * 384 * 2);
    short* we1l   = (short*)carve((size_t)3 * 128 * 384 * 2);
    short* we2h   = (short*)carve((size_t)3 * 128 * 128 * 2);
    short* we2l   = (short*)carve((size_t)3 * 128 * 128 * 2);
    short* wn1h   = (short*)carve((size_t)3 * 128 * 256 * 2);
    short* wn1l   = (short*)carve((size_t)3 * 128 * 256 * 2);
    short* wn2h   = (short*)carve((size_t)3 * 128 * 128 * 2);
    short* wn2l   = (short*)carve((size_t)3 * 128 * 128 * 2);
    short* wf1h   = (short*)carve((size_t)128 * 384 * 2);
    short* wf1l   = (short*)carve((size_t)128 * 384 * 2);
    short* wf2h   = (short*)carve((size_t)128 * 128 * 2);
    short* wf2l   = (short*)carve((size_t)128 * 128 * 2);

    const int TB = 256;
    const int gN  = (NNc + TB - 1) / TB;
    const int gE  = (NEc + TB - 1) / TB;

    for (int i = 0; i < 3; i++) {
        k_wconv2<<<(128 * 384 + 255) / 256, TB, 0, stream>>>(We1 + (size_t)i * 384 * 128, we1h + (size_t)i * 128 * 384, we1l + (size_t)i * 128 * 384, 384);
        k_wconv2<<<(128 * 128 + 255) / 256, TB, 0, stream>>>(We2 + (size_t)i * 128 * 128, we2h + (size_t)i * 128 * 128, we2l + (size_t)i * 128 * 128, 128);
        k_wconv2<<<(128 * 256 + 255) / 256, TB, 0, stream>>>(Wn1 + (size_t)i * 256 * 128, wn1h + (size_t)i * 128 * 256, wn1l + (size_t)i * 128 * 256, 256);
        k_wconv2<<<(128 * 128 + 255) / 256, TB, 0, stream>>>(Wn2 + (size_t)i * 128 * 128, wn2h + (size_t)i * 128 * 128, wn2l + (size_t)i * 128 * 128, 128);
    }
    k_wconv2<<<(128 * 384 + 255) / 256, TB, 0, stream>>>(Wf1, wf1h, wf1l, 384);
    k_wconv2<<<(128 * 128 + 255) / 256, TB, 0, stream>>>(Wf2, wf2h, wf2l, 128);

    // CSR build
    k_zero_i<<<gN, TB, 0, stream>>>(deg, NNc);
    k_count<<<gE, TB, 0, stream>>>(rcvr, deg);
    k_scan<<<1, TB, 0, stream>>>(deg, rowst, cursor);
    k_scatter<<<gE, TB, 0, stream>>>(sndr, rcvr, cursor, csr_se);

    // initial flows
    k_qinit<<<gE, TB, 0, stream>>>(x, r, sndr, rcvr, qh, qt);

    float* hcur = hA;
    float* hnxt = hB;
    for (int kit = 0; kit < 4; kit++) {
        // g = split-selu planes of selu([segsum(qh), d_star]) @ Wni
        k_node_in_f<<<(NNc + 3) / 4, TB, 0, stream>>>(qh, rowst, csr_se, x, Wni, gh_u, gl_u);
        // edge/node message-passing layers; z planes ping-pong A<->B
        unsigned *zin_h = zAh, *zin_l = zAl, *zout_h = zAh, *zout_l = zAl;
        for (int i = 0; i < 3; i++) {
            zin_h = zout_h; zin_l = zout_l;
            zout_h = (i & 1) ? zAh : zBh;
            zout_l = (i & 1) ? zAl : zBl;
            k_edge_mlp_mfma<<<NEc / 32, 512, 0, stream>>>(
                gh_u, gl_u, zin_h, zin_l, zout_h, zout_l,
                we1h + (size_t)i * 128 * 384, we1l + (size_t)i * 128 * 384,
                we2h + (size_t)i * 128 * 128, we2l + (size_t)i * 128 * 128,
                sndr, rcvr, qt, qh, Wei, (i == 0) ? 1 : 0);
            k_node_mlp_mfma<<<NNc / 32, 512, 0, stream>>>(
                gh_u, gl_u, gh_u, gl_u, zout_h, zout_l, rowst, csr_se,
                wn1h + (size_t)i * 128 * 256, wn1l + (size_t)i * 128 * 256,
                wn2h + (size_t)i * 128 * 128, wn2l + (size_t)i * 128 * 128);
        }
        k_wf_mfma<<<(4 * E2c) / 32, 512, 0, stream>>>(
            gh_u, gl_u, zout_h, zout_l, wf1h, wf1l, wf2h, wf2l, Wf3, sndr, rcvr, qh);
        // heads
        k_hl_copy<<<gE, TB, 0, stream>>>(qh, r, x, hl, hcur);
        for (int jh = 0; jh < 6; jh++) {
            float* dst = (kit == 3 && jh == 5) ? out : hnxt;
            k_head_iter<<<gN, TB, 0, stream>>>(x, hcur, hl, rowst, csr_se, dst);
            float* tmp = hcur; hcur = (kit == 3 && jh == 5) ? hcur : hnxt;
            if (!(kit == 3 && jh == 5)) hnxt = tmp;
        }
        if (kit < 3) k_flows_q<<<gE, TB, 0, stream>>>(hcur, r, sndr, rcvr, qt);
    }
}

// Round 6
// 2622.221 us; speedup vs baseline: 2.9780x; 1.3219x over previous
//
#include <hip/hip_runtime.h>
#include <hip/hip_bf16.h>
#include <math.h>

// Problem constants
#define NPGc  10000
#define EPGc  32000
#define MLc   128
#define NNc   40000      // N
#define NEc   128000     // E
#define E2c   16000      // EPG/2
#define ZETAc 1e-6f
#define INVPc 0.53995680345572354f   // 1/1.852
#define PEXPc 1.852f

typedef __attribute__((ext_vector_type(8))) short short8;   // 8 bf16 (4 VGPRs)
typedef __attribute__((ext_vector_type(4))) float f32x4;    // MFMA acc

// fast selu: __expf -> v_exp_f32
__device__ __forceinline__ float selu_f(float x) {
    float e = __expf(x) - 1.0f;
    return 1.0507009873554805f * (x > 0.0f ? x : 1.6732632423543772f * e);
}
// split fp32 -> (hi, lo) bf16 pair: v ~= hi + lo, residual ~2^-18 relative
__device__ __forceinline__ void splitu(float v, unsigned& hi, unsigned& lo) {
    __hip_bfloat16 h = __float2bfloat16(v);
    hi = (unsigned short)*reinterpret_cast<short*>(&h);
    float rem = v - __bfloat162float(h);
    __hip_bfloat16 l = __float2bfloat16(rem);
    lo = (unsigned short)*reinterpret_cast<short*>(&l);
}
__device__ __forceinline__ float signf(float x) {
    return (x > 0.0f) ? 1.0f : (x < 0.0f ? -1.0f : 0.0f);
}

// ---------------- weight convert+split into MFMA B-FRAGMENT-LINEAR layout ------------
// src: [K][128] fp32. dst (hi/lo): fragment order
//   dst[(((ct*nkc)+kc)*64 + lane)*8 + j] = split(src[kc*32 + (lane>>4)*8 + j][ct*16 + (lane&15)])
// so a wave's B-load is base + lane*16B: ONE contiguous 1KB segment (8 lines, not 64).
__global__ void k_wconv_frag(const float* __restrict__ src, short* __restrict__ dh,
                             short* __restrict__ dl, int nkc /* = K/32 */) {
    int gid = blockIdx.x * 256 + threadIdx.x;   // one thread per (frag, lane)
    int total = 8 * nkc * 64;                   // ct(8) x kc(nkc) x lane(64)
    if (gid >= total) return;
    int lane = gid & 63;
    int frag = gid >> 6;
    int kc = frag % nkc;
    int ct = frag / nkc;
    int col = ct * 16 + (lane & 15);
    int kbase = kc * 32 + (lane >> 4) * 8;
    size_t o = (size_t)gid * 8;
#pragma unroll
    for (int j = 0; j < 8; j++) {
        unsigned h, l;
        splitu(src[(size_t)(kbase + j) * 128 + col], h, l);
        dh[o + j] = (short)h;
        dl[o + j] = (short)l;
    }
}

// ---------------- CSR build (by rcvr) ----------------
__global__ void k_zero_i(int* p, int n) {
    int i = blockIdx.x * 256 + threadIdx.x;
    if (i < n) p[i] = 0;
}
__global__ void k_count(const int* __restrict__ rcvr, int* __restrict__ deg) {
    int e = blockIdx.x * 256 + threadIdx.x;
    if (e < NEc) atomicAdd(&deg[rcvr[e]], 1);
}
__global__ void k_scan(const int* __restrict__ deg, int* __restrict__ rowstart,
                       int* __restrict__ cursor) {
    __shared__ int sums[256];
    const int tid = threadIdx.x;
    const int CH = (NNc + 255) / 256;
    const int i0 = tid * CH;
    int s = 0;
    for (int j = 0; j < CH; j++) {
        int i = i0 + j;
        if (i < NNc) s += deg[i];
    }
    sums[tid] = s;
    __syncthreads();
    for (int off = 1; off < 256; off <<= 1) {
        int t = (tid >= off) ? sums[tid - off] : 0;
        __syncthreads();
        sums[tid] += t;
        __syncthreads();
    }
    int base = sums[tid] - s;
    for (int j = 0; j < CH; j++) {
        int i = i0 + j;
        if (i < NNc) {
            rowstart[i] = base;
            cursor[i] = base;
            base += deg[i];
        }
    }
    if (tid == 255) rowstart[NNc] = base;
}
__global__ void k_scatter(const int* __restrict__ sndr, const int* __restrict__ rcvr,
                          int* __restrict__ cursor, int2* __restrict__ csr_se) {
    int e = blockIdx.x * 256 + threadIdx.x;
    if (e >= NEc) return;
    int rv = rcvr[e];
    int p = atomicAdd(&cursor[rv], 1);
    csr_se[p] = make_int2(sndr[e], e);
}

// ---------------- flows / elementwise ----------------
__global__ void k_qinit(const float* __restrict__ x, const float* __restrict__ r,
                        const int* __restrict__ sndr, const int* __restrict__ rcvr,
                        float* __restrict__ qh, float* __restrict__ qt) {
    int e = blockIdx.x * 256 + threadIdx.x;
    if (e >= NEc) return;
    float hv = x[2 * sndr[e]] - x[2 * rcvr[e]];
    float q = signf(hv) * __powf((fabsf(hv) + ZETAc) / (r[e] + ZETAc), INVPc);
    qh[e] = q; qt[e] = q;
}
__global__ void k_flows_q(const float* __restrict__ h, const float* __restrict__ r,
                          const int* __restrict__ sndr, const int* __restrict__ rcvr,
                          float* __restrict__ qt) {
    int e = blockIdx.x * 256 + threadIdx.x;
    if (e >= NEc) return;
    float hv = h[sndr[e]] - h[rcvr[e]];
    qt[e] = signf(hv) * __powf((fabsf(hv) + ZETAc) / (r[e] + ZETAc), INVPc);
}

// node-in, fused segsum: one WAVE per node. Produces split-selu g planes.
__global__ __launch_bounds__(256) void k_node_in_f(
    const float* __restrict__ qh, const int* __restrict__ rowstart,
    const int2* __restrict__ csr_se, const float* __restrict__ x,
    const float* __restrict__ W /*2x128*/,
    unsigned* __restrict__ gh_u, unsigned* __restrict__ gl_u) {
    const int tid = threadIdx.x;
    const int lane = tid & 63;
    const int n = blockIdx.x * 4 + (tid >> 6);
    if (n >= NNc) return;
    int p0 = rowstart[n], p1 = rowstart[n + 1];
    float s = 0.0f;
    for (int p = p0 + lane; p < p1; p += 64) s += qh[csr_se[p].y];
#pragma unroll
    for (int off = 1; off < 64; off <<= 1) s += __shfl_xor(s, off, 64);
    float s0 = selu_f(s);
    float s1 = selu_f(x[2 * n + 1]);
    int c = lane * 2;
    float g0 = s0 * W[c]     + s1 * W[MLc + c];
    float g1 = s0 * W[c + 1] + s1 * W[MLc + c + 1];
    unsigned h0, l0, h1, l1;
    splitu(selu_f(g0), h0, l0);
    splitu(selu_f(g1), h1, l1);
    gh_u[(size_t)n * 64 + lane] = h0 | (h1 << 16);
    gl_u[(size_t)n * 64 + lane] = l0 | (l1 << 16);
}

// hl + copy_h fused
__global__ void k_hl_copy(const float* __restrict__ qh, const float* __restrict__ r,
                          const float* __restrict__ x,
                          float* __restrict__ hl, float* __restrict__ h) {
    int i = blockIdx.x * 256 + threadIdx.x;
    if (i < NEc) {
        float q = qh[i];
        hl[i] = r[i] * signf(q) * __powf(fabsf(q), PEXPc);
    }
    if (i < NNc) h[i] = x[2 * i];
}
// one head-propagation iteration, CSR gather, ping-pong
__global__ void k_head_iter(const float* __restrict__ x, const float* __restrict__ hin,
                            const float* __restrict__ hl, const int* __restrict__ rowstart,
                            const int2* __restrict__ csr_se, float* __restrict__ hout) {
    int n = blockIdx.x * 256 + threadIdx.x;
    if (n >= NNc) return;
    float hv = hin[n];
    float m = -3.0e38f;
    int p0 = rowstart[n], p1 = rowstart[n + 1];
    for (int p = p0; p < p1; p++) {
        int2 se = csr_se[p];
        m = fmaxf(m, hin[se.x] - hl[se.y]);
    }
    float a = (m > -1e30f) ? m : hv;
    float hstar = x[2 * n];
    hout[n] = (hstar != 0.0f) ? hstar : fmaxf(hv, a);
}

// ---------------- split-bf16 MFMA MLP kernels ----------------
// Inputs arrive as pre-split selu planes (h/l shorts, 2 cols packed per dword).
// Weights arrive fragment-linear (see k_wconv_frag): B-load = base + lane*16B.
// 32-row tile, 512 threads = 8 waves; wave = 16-col tile x both 16-row tiles.
// A-frag: row=lane&15, k=quad*8+j. C/D: col=lane&15, row=quad*4+reg.

#define MS_E 392   // 384+8 shorts
#define MS_N 264   // 256+8
#define TS   136   // 128+8

// epilogue pack helper: lane parity selects hi/lo plane dword
__device__ __forceinline__ void pack_pair(unsigned h, unsigned l, bool ev,
                                          unsigned& word) {
    unsigned oh = __shfl_xor((int)h, 1, 64);
    unsigned ol = __shfl_xor((int)l, 1, 64);
    unsigned wh = ev ? (h | (oh << 16)) : (oh | (h << 16));
    unsigned wl = ev ? (l | (ol << 16)) : (ol | (l << 16));
    word = ev ? wh : wl;
}

__global__ __launch_bounds__(512) void k_edge_mlp_mfma(
    const unsigned* __restrict__ gh_u, const unsigned* __restrict__ gl_u,
    const unsigned* __restrict__ zh_u, const unsigned* __restrict__ zl_u,
    unsigned* __restrict__ zoh_u, unsigned* __restrict__ zol_u,
    const short* __restrict__ W1h, const short* __restrict__ W1l,
    const short* __restrict__ W2h, const short* __restrict__ W2l,
    const int* __restrict__ sndr, const int* __restrict__ rcvr,
    const float* __restrict__ qt, const float* __restrict__ qh,
    const float* __restrict__ Wei, int zmode) {
    __shared__ short smem[2 * 32 * MS_E];        // 50176 B
    short* m_hi = smem;
    short* m_lo = smem + 32 * MS_E;
    short* t_hi = smem;                          // alias front (post-barrier)
    short* t_lo = smem + 32 * TS;
    const int tid = threadIdx.x;
    const int e0 = blockIdx.x * 32;

    for (int idx = tid; idx < 32 * 192; idx += 512) {
        int row = idx / 192, pp = idx - row * 192;
        int region = pp >> 6, cp = pp & 63;
        int e = e0 + row;
        unsigned uh, ul;
        if (region == 0) {
            size_t o = (size_t)sndr[e] * 64 + cp;
            uh = gh_u[o]; ul = gl_u[o];
        } else if (region == 1) {
            size_t o = (size_t)rcvr[e] * 64 + cp;
            uh = gh_u[o]; ul = gl_u[o];
        } else if (zmode == 0) {
            size_t o = (size_t)e * 64 + cp;
            uh = zh_u[o]; ul = zl_u[o];
        } else {
            float sqt = selu_f(qt[e]), sqh = selu_f(qh[e]);
            int c = 2 * cp;
            float z0 = sqt * Wei[c]     + sqh * Wei[MLc + c];
            float z1 = sqt * Wei[c + 1] + sqh * Wei[MLc + c + 1];
            unsigned h0, l0, h1, l1;
            splitu(selu_f(z0), h0, l0);
            splitu(selu_f(z1), h1, l1);
            uh = h0 | (h1 << 16); ul = l0 | (l1 << 16);
        }
        int k = region * 128 + 2 * cp;
        *(unsigned*)&m_hi[row * MS_E + k] = uh;
        *(unsigned*)&m_lo[row * MS_E + k] = ul;
    }
    __syncthreads();

    const int lane = tid & 63, ct = tid >> 6;
    const int l15 = lane & 15, quad = lane >> 4;
    const bool ev = (l15 & 1) == 0;
    const int col = ct * 16 + l15;

    f32x4 acc[2];
    acc[0] = (f32x4){0.f, 0.f, 0.f, 0.f};
    acc[1] = (f32x4){0.f, 0.f, 0.f, 0.f};
#pragma unroll 4
    for (int kc = 0; kc < 12; kc++) {
        size_t wo = ((size_t)(ct * 12 + kc) * 64 + lane) * 8;   // fragment-linear
        short8 bh = *(const short8*)&W1h[wo];
        short8 bl = *(const short8*)&W1l[wo];
#pragma unroll
        for (int rt = 0; rt < 2; rt++) {
            const short* ap = &m_hi[(rt * 16 + l15) * MS_E + kc * 32 + quad * 8];
            short8 ah = *(const short8*)ap;
            short8 al = *(const short8*)(ap + 32 * MS_E);
            acc[rt] = __builtin_amdgcn_mfma_f32_16x16x32_bf16(ah, bh, acc[rt], 0, 0, 0);
            acc[rt] = __builtin_amdgcn_mfma_f32_16x16x32_bf16(al, bh, acc[rt], 0, 0, 0);
            acc[rt] = __builtin_amdgcn_mfma_f32_16x16x32_bf16(ah, bl, acc[rt], 0, 0, 0);
        }
    }
    __syncthreads();
#pragma unroll
    for (int rt = 0; rt < 2; rt++) {
#pragma unroll
        for (int rr = 0; rr < 4; rr++) {
            unsigned h, l, word;
            splitu(selu_f(acc[rt][rr]), h, l);
            pack_pair(h, l, ev, word);
            short* basep = ev ? t_hi : t_lo;
            *(unsigned*)&basep[(rt * 16 + quad * 4 + rr) * TS + (col & ~1)] = word;
        }
    }
    __syncthreads();

    f32x4 acc2[2];
    acc2[0] = (f32x4){0.f, 0.f, 0.f, 0.f};
    acc2[1] = (f32x4){0.f, 0.f, 0.f, 0.f};
#pragma unroll
    for (int kc = 0; kc < 4; kc++) {
        size_t wo = ((size_t)(ct * 4 + kc) * 64 + lane) * 8;
        short8 bh = *(const short8*)&W2h[wo];
        short8 bl = *(const short8*)&W2l[wo];
#pragma unroll
        for (int rt = 0; rt < 2; rt++) {
            const short* ap = &t_hi[(rt * 16 + l15) * TS + kc * 32 + quad * 8];
            short8 ah = *(const short8*)ap;
            short8 al = *(const short8*)(ap + 32 * TS);
            acc2[rt] = __builtin_amdgcn_mfma_f32_16x16x32_bf16(ah, bh, acc2[rt], 0, 0, 0);
            acc2[rt] = __builtin_amdgcn_mfma_f32_16x16x32_bf16(al, bh, acc2[rt], 0, 0, 0);
            acc2[rt] = __builtin_amdgcn_mfma_f32_16x16x32_bf16(ah, bl, acc2[rt], 0, 0, 0);
        }
    }
    // write z output planes: split(selu(z_raw)) packed
#pragma unroll
    for (int rt = 0; rt < 2; rt++) {
#pragma unroll
        for (int rr = 0; rr < 4; rr++) {
            unsigned h, l, word;
            splitu(selu_f(acc2[rt][rr]), h, l);
            pack_pair(h, l, ev, word);
            unsigned* plane = ev ? zoh_u : zol_u;
            plane[(size_t)(e0 + rt * 16 + quad * 4 + rr) * 64 + (col >> 1)] = word;
        }
    }
}

// node MLP: staging gathers g planes + selu-space segment max of z planes
__global__ __launch_bounds__(512) void k_node_mlp_mfma(
    const unsigned* __restrict__ gh_u, const unsigned* __restrict__ gl_u,
    unsigned* __restrict__ goh_u, unsigned* __restrict__ gol_u,
    const unsigned* __restrict__ zh_u, const unsigned* __restrict__ zl_u,
    const int* __restrict__ rowstart, const int2* __restrict__ csr_se,
    const short* __restrict__ W1h, const short* __restrict__ W1l,
    const short* __restrict__ W2h, const short* __restrict__ W2l) {
    __shared__ short smem[2 * 32 * MS_N];        // 33792 B
    short* m_hi = smem;
    short* m_lo = smem + 32 * MS_N;
    short* t_hi = smem;
    short* t_lo = smem + 32 * TS;
    const int tid = threadIdx.x;
    const int n0 = blockIdx.x * 32;

    for (int idx = tid; idx < 32 * 128; idx += 512) {
        int row = idx >> 7, pp = idx & 127;
        int region = pp >> 6, cp = pp & 63;
        int n = n0 + row;
        unsigned uh, ul;
        if (region == 0) {
            size_t o = (size_t)n * 64 + cp;
            uh = gh_u[o]; ul = gl_u[o];
        } else {
            // segment max in selu space over CSR edges (selu monotone)
            int p0 = rowstart[n], p1 = rowstart[n + 1];
            float b0 = -3.0e38f, b1 = -3.0e38f;
            unsigned bh0 = 0, bl0 = 0, bh1 = 0, bl1 = 0;  // default split(0)
            for (int p = p0; p < p1; p++) {
                size_t o = (size_t)csr_se[p].y * 64 + cp;
                unsigned vh = zh_u[o], vl = zl_u[o];
                float f0 = __uint_as_float(vh << 16) + __uint_as_float(vl << 16);
                float f1 = __uint_as_float(vh & 0xffff0000u) + __uint_as_float(vl & 0xffff0000u);
                if (f0 > b0) { b0 = f0; bh0 = vh & 0xffffu; bl0 = vl & 0xffffu; }
                if (f1 > b1) { b1 = f1; bh1 = vh & 0xffff0000u; bl1 = vl & 0xffff0000u; }
            }
            uh = bh0 | bh1; ul = bl0 | bl1;
        }
        int k = region * 128 + 2 * cp;
        *(unsigned*)&m_hi[row * MS_N + k] = uh;
        *(unsigned*)&m_lo[row * MS_N + k] = ul;
    }
    __syncthreads();

    const int lane = tid & 63, ct = tid >> 6;
    const int l15 = lane & 15, quad = lane >> 4;
    const bool ev = (l15 & 1) == 0;
    const int col = ct * 16 + l15;

    f32x4 acc[2];
    acc[0] = (f32x4){0.f, 0.f, 0.f, 0.f};
    acc[1] = (f32x4){0.f, 0.f, 0.f, 0.f};
#pragma unroll 4
    for (int kc = 0; kc < 8; kc++) {
        size_t wo = ((size_t)(ct * 8 + kc) * 64 + lane) * 8;
        short8 bh = *(const short8*)&W1h[wo];
        short8 bl = *(const short8*)&W1l[wo];
#pragma unroll
        for (int rt = 0; rt < 2; rt++) {
            const short* ap = &m_hi[(rt * 16 + l15) * MS_N + kc * 32 + quad * 8];
            short8 ah = *(const short8*)ap;
            short8 al = *(const short8*)(ap + 32 * MS_N);
            acc[rt] = __builtin_amdgcn_mfma_f32_16x16x32_bf16(ah, bh, acc[rt], 0, 0, 0);
            acc[rt] = __builtin_amdgcn_mfma_f32_16x16x32_bf16(al, bh, acc[rt], 0, 0, 0);
            acc[rt] = __builtin_amdgcn_mfma_f32_16x16x32_bf16(ah, bl, acc[rt], 0, 0, 0);
        }
    }
    __syncthreads();
#pragma unroll
    for (int rt = 0; rt < 2; rt++) {
#pragma unroll
        for (int rr = 0; rr < 4; rr++) {
            unsigned h, l, word;
            splitu(selu_f(acc[rt][rr]), h, l);
            pack_pair(h, l, ev, word);
            short* basep = ev ? t_hi : t_lo;
            *(unsigned*)&basep[(rt * 16 + quad * 4 + rr) * TS + (col & ~1)] = word;
        }
    }
    __syncthreads();

    f32x4 acc2[2];
    acc2[0] = (f32x4){0.f, 0.f, 0.f, 0.f};
    acc2[1] = (f32x4){0.f, 0.f, 0.f, 0.f};
#pragma unroll
    for (int kc = 0; kc < 4; kc++) {
        size_t wo = ((size_t)(ct * 4 + kc) * 64 + lane) * 8;
        short8 bh = *(const short8*)&W2h[wo];
        short8 bl = *(const short8*)&W2l[wo];
#pragma unroll
        for (int rt = 0; rt < 2; rt++) {
            const short* ap = &t_hi[(rt * 16 + l15) * TS + kc * 32 + quad * 8];
            short8 ah = *(const short8*)ap;
            short8 al = *(const short8*)(ap + 32 * TS);
            acc2[rt] = __builtin_amdgcn_mfma_f32_16x16x32_bf16(ah, bh, acc2[rt], 0, 0, 0);
            acc2[rt] = __builtin_amdgcn_mfma_f32_16x16x32_bf16(al, bh, acc2[rt], 0, 0, 0);
            acc2[rt] = __builtin_amdgcn_mfma_f32_16x16x32_bf16(ah, bl, acc2[rt], 0, 0, 0);
        }
    }
#pragma unroll
    for (int rt = 0; rt < 2; rt++) {
#pragma unroll
        for (int rr = 0; rr < 4; rr++) {
            unsigned h, l, word;
            splitu(selu_f(acc2[rt][rr]), h, l);
            pack_pair(h, l, ev, word);
            unsigned* plane = ev ? goh_u : gol_u;
            plane[(size_t)(n0 + rt * 16 + quad * 4 + rr) * 64 + (col >> 1)] = word;
        }
    }
}

// Wf chain on first-half edges: q_new = q_old + selu(selu(lam@Wf1)@Wf2)@Wf3; antisymmetrize.
__global__ __launch_bounds__(512) void k_wf_mfma(
    const unsigned* __restrict__ gh_u, const unsigned* __restrict__ gl_u,
    const unsigned* __restrict__ zh_u, const unsigned* __restrict__ zl_u,
    const short* __restrict__ W1h, const short* __restrict__ W1l,
    const short* __restrict__ W2h, const short* __restrict__ W2l,
    const float* __restrict__ W3 /*[128]*/,
    const int* __restrict__ sndr, const int* __restrict__ rcvr,
    float* __restrict__ qh) {
    __shared__ short smem[2 * 32 * MS_E];
    __shared__ float red[32 * 8];
    short* m_hi = smem;
    short* m_lo = smem + 32 * MS_E;
    short* t_hi = smem;
    short* t_lo = smem + 32 * TS;
    const int tid = threadIdx.x;
    const int fi0 = blockIdx.x * 32;
    const int b = fi0 / E2c;
    const int ebase = b * EPGc - b * E2c;     // e = ebase + fi

    for (int idx = tid; idx < 32 * 192; idx += 512) {
        int row = idx / 192, pp = idx - row * 192;
        int region = pp >> 6, cp = pp & 63;
        int e = ebase + fi0 + row;
        size_t o;
        const unsigned *ph, *pl;
        if (region == 0)      { o = (size_t)sndr[e] * 64 + cp; ph = gh_u; pl = gl_u; }
        else if (region == 1) { o = (size_t)rcvr[e] * 64 + cp; ph = gh_u; pl = gl_u; }
        else                  { o = (size_t)e * 64 + cp;       ph = zh_u; pl = zl_u; }
        int k = region * 128 + 2 * cp;
        *(unsigned*)&m_hi[row * MS_E + k] = ph[o];
        *(unsigned*)&m_lo[row * MS_E + k] = pl[o];
    }
    __syncthreads();

    const int lane = tid & 63, ct = tid >> 6;
    const int l15 = lane & 15, quad = lane >> 4;
    const bool ev = (l15 & 1) == 0;
    const int col = ct * 16 + l15;

    f32x4 acc[2];
    acc[0] = (f32x4){0.f, 0.f, 0.f, 0.f};
    acc[1] = (f32x4){0.f, 0.f, 0.f, 0.f};
#pragma unroll 4
    for (int kc = 0; kc < 12; kc++) {
        size_t wo = ((size_t)(ct * 12 + kc) * 64 + lane) * 8;
        short8 bh = *(const short8*)&W1h[wo];
        short8 bl = *(const short8*)&W1l[wo];
#pragma unroll
        for (int rt = 0; rt < 2; rt++) {
            const short* ap = &m_hi[(rt * 16 + l15) * MS_E + kc * 32 + quad * 8];
            short8 ah = *(const short8*)ap;
            short8 al = *(const short8*)(ap + 32 * MS_E);
            acc[rt] = __builtin_amdgcn_mfma_f32_16x16x32_bf16(ah, bh, acc[rt], 0, 0, 0);
            acc[rt] = __builtin_amdgcn_mfma_f32_16x16x32_bf16(al, bh, acc[rt], 0, 0, 0);
            acc[rt] = __builtin_amdgcn_mfma_f32_16x16x32_bf16(ah, bl, acc[rt], 0, 0, 0);
        }
    }
    __syncthreads();
#pragma unroll
    for (int rt = 0; rt < 2; rt++) {
#pragma unroll
        for (int rr = 0; rr < 4; rr++) {
            unsigned h, l, word;
            splitu(selu_f(acc[rt][rr]), h, l);
            pack_pair(h, l, ev, word);
            short* basep = ev ? t_hi : t_lo;
            *(unsigned*)&basep[(rt * 16 + quad * 4 + rr) * TS + (col & ~1)] = word;
        }
    }
    __syncthreads();

    f32x4 acc2[2];
    acc2[0] = (f32x4){0.f, 0.f, 0.f, 0.f};
    acc2[1] = (f32x4){0.f, 0.f, 0.f, 0.f};
#pragma unroll
    for (int kc = 0; kc < 4; kc++) {
        size_t wo = ((size_t)(ct * 4 + kc) * 64 + lane) * 8;
        short8 bh = *(const short8*)&W2h[wo];
        short8 bl = *(const short8*)&W2l[wo];
#pragma unroll
        for (int rt = 0; rt < 2; rt++) {
            const short* ap = &t_hi[(rt * 16 + l15) * TS + kc * 32 + quad * 8];
            short8 ah = *(const short8*)ap;
            short8 al = *(const short8*)(ap + 32 * TS);
            acc2[rt] = __builtin_amdgcn_mfma_f32_16x16x32_bf16(ah, bh, acc2[rt], 0, 0, 0);
            acc2[rt] = __builtin_amdgcn_mfma_f32_16x16x32_bf16(al, bh, acc2[rt], 0, 0, 0);
            acc2[rt] = __builtin_amdgcn_mfma_f32_16x16x32_bf16(ah, bl, acc2[rt], 0, 0, 0);
        }
    }
    float w3 = W3[col];
    float p[8];
#pragma unroll
    for (int rt = 0; rt < 2; rt++)
#pragma unroll
        for (int rr = 0; rr < 4; rr++) p[rt * 4 + rr] = selu_f(acc2[rt][rr]) * w3;
#pragma unroll
    for (int off = 1; off < 16; off <<= 1) {
#pragma unroll
        for (int i = 0; i < 8; i++) p[i] += __shfl_xor(p[i], off, 64);
    }
    if (l15 == 0) {
#pragma unroll
        for (int rt = 0; rt < 2; rt++)
#pragma unroll
            for (int rr = 0; rr < 4; rr++)
                red[(rt * 16 + quad * 4 + rr) * 8 + ct] = p[rt * 4 + rr];
    }
    __syncthreads();
    if (tid < 32) {
        float f = 0.0f;
#pragma unroll
        for (int c = 0; c < 8; c++) f += red[tid * 8 + c];
        int e = ebase + fi0 + tid;
        float qn = qh[e] + f;
        qh[e] = qn;
        qh[e + E2c] = -qn;
    }
}

// ---------------- host orchestration ----------------

extern "C" void kernel_launch(void* const* d_in, const int* in_sizes, int n_in,
                              void* d_out, int out_size, void* d_ws, size_t ws_size,
                              hipStream_t stream) {
    const float* x   = (const float*)d_in[0];
    const float* r   = (const float*)d_in[1];
    const float* Wni = (const float*)d_in[2];
    const float* Wei = (const float*)d_in[3];
    const float* Wf1 = (const float*)d_in[4];
    const float* Wf2 = (const float*)d_in[5];
    const float* Wf3 = (const float*)d_in[6];
    const float* We1 = (const float*)d_in[7];   // (3,384,128)
    const float* We2 = (const float*)d_in[8];   // (3,128,128)
    const float* Wn1 = (const float*)d_in[9];   // (3,256,128)
    const float* Wn2 = (const float*)d_in[10];  // (3,128,128)
    const int* sndr  = (const int*)d_in[11];
    const int* rcvr  = (const int*)d_in[12];
    float* out = (float*)d_out;

    char* wp = (char*)d_ws;
    auto carve = [&](size_t bytes) -> void* {
        void* ret = (void*)wp;
        wp += (bytes + 255) & ~(size_t)255;
        return ret;
    };
    unsigned* gh_u = (unsigned*)carve((size_t)NNc * 64 * 4);
    unsigned* gl_u = (unsigned*)carve((size_t)NNc * 64 * 4);
    unsigned* zAh  = (unsigned*)carve((size_t)NEc * 64 * 4);
    unsigned* zAl  = (unsigned*)carve((size_t)NEc * 64 * 4);
    unsigned* zBh  = (unsigned*)carve((size_t)NEc * 64 * 4);
    unsigned* zBl  = (unsigned*)carve((size_t)NEc * 64 * 4);
    float* qh     = (float*)carve((size_t)NEc * 4);
    float* qt     = (float*)carve((size_t)NEc * 4);
    float* hl     = (float*)carve((size_t)NEc * 4);
    float* hA     = (float*)carve((size_t)NNc * 4);
    float* hB     = (float*)carve((size_t)NNc * 4);
    int*   deg    = (int*)carve((size_t)NNc * 4);
    int*   cursor = (int*)carve((size_t)NNc * 4);
    int*   rowst  = (int*)carve((size_t)(NNc + 1) * 4);
    int2*  csr_se = (int2*)carve((size_t)NEc * 8);
    short* we1h   = (short*)carve((size_t)3 * 128 * 384 * 2);
    short* we1l   = (short*)carve((size_t)3 * 128 * 384 * 2);
    short* we2h   = (short*)carve((size_t)3 * 128 * 128 * 2);
    short* we2l   = (short*)carve((size_t)3 * 128 * 128 * 2);
    short* wn1h   = (short*)carve((size_t)3 * 128 * 256 * 2);
    short* wn1l   = (short*)carve((size_t)3 * 128 * 256 * 2);
    short* wn2h   = (short*)carve((size_t)3 * 128 * 128 * 2);
    short* wn2l   = (short*)carve((size_t)3 * 128 * 128 * 2);
    short* wf1h   = (short*)carve((size_t)128 * 384 * 2);
    short* wf1l   = (short*)carve((size_t)128 * 384 * 2);
    short* wf2h   = (short*)carve((size_t)128 * 128 * 2);
    short* wf2l   = (short*)carve((size_t)128 * 128 * 2);

    const int TB = 256;
    const int gN  = (NNc + TB - 1) / TB;
    const int gE  = (NEc + TB - 1) / TB;

    // fragment-linear weight planes (nkc = K/32): grid = 8*nkc*64 threads
    for (int i = 0; i < 3; i++) {
        k_wconv_frag<<<(8 * 12 * 64 + 255) / 256, TB, 0, stream>>>(We1 + (size_t)i * 384 * 128, we1h + (size_t)i * 128 * 384, we1l + (size_t)i * 128 * 384, 12);
        k_wconv_frag<<<(8 * 4 * 64 + 255) / 256, TB, 0, stream>>>(We2 + (size_t)i * 128 * 128, we2h + (size_t)i * 128 * 128, we2l + (size_t)i * 128 * 128, 4);
        k_wconv_frag<<<(8 * 8 * 64 + 255) / 256, TB, 0, stream>>>(Wn1 + (size_t)i * 256 * 128, wn1h + (size_t)i * 128 * 256, wn1l + (size_t)i * 128 * 256, 8);
        k_wconv_frag<<<(8 * 4 * 64 + 255) / 256, TB, 0, stream>>>(Wn2 + (size_t)i * 128 * 128, wn2h + (size_t)i * 128 * 128, wn2l + (size_t)i * 128 * 128, 4);
    }
    k_wconv_frag<<<(8 * 12 * 64 + 255) / 256, TB, 0, stream>>>(Wf1, wf1h, wf1l, 12);
    k_wconv_frag<<<(8 * 4 * 64 + 255) / 256, TB, 0, stream>>>(Wf2, wf2h, wf2l, 4);

    // CSR build
    k_zero_i<<<gN, TB, 0, stream>>>(deg, NNc);
    k_count<<<gE, TB, 0, stream>>>(rcvr, deg);
    k_scan<<<1, TB, 0, stream>>>(deg, rowst, cursor);
    k_scatter<<<gE, TB, 0, stream>>>(sndr, rcvr, cursor, csr_se);

    // initial flows
    k_qinit<<<gE, TB, 0, stream>>>(x, r, sndr, rcvr, qh, qt);

    float* hcur = hA;
    float* hnxt = hB;
    for (int kit = 0; kit < 4; kit++) {
        // g = split-selu planes of selu([segsum(qh), d_star]) @ Wni
        k_node_in_f<<<(NNc + 3) / 4, TB, 0, stream>>>(qh, rowst, csr_se, x, Wni, gh_u, gl_u);
        // edge/node message-passing layers; z planes ping-pong A<->B
        unsigned *zin_h = zAh, *zin_l = zAl, *zout_h = zAh, *zout_l = zAl;
        for (int i = 0; i < 3; i++) {
            zin_h = zout_h; zin_l = zout_l;
            zout_h = (i & 1) ? zAh : zBh;
            zout_l = (i & 1) ? zAl : zBl;
            k_edge_mlp_mfma<<<NEc / 32, 512, 0, stream>>>(
                gh_u, gl_u, zin_h, zin_l, zout_h, zout_l,
                we1h + (size_t)i * 128 * 384, we1l + (size_t)i * 128 * 384,
                we2h + (size_t)i * 128 * 128, we2l + (size_t)i * 128 * 128,
                sndr, rcvr, qt, qh, Wei, (i == 0) ? 1 : 0);
            k_node_mlp_mfma<<<NNc / 32, 512, 0, stream>>>(
                gh_u, gl_u, gh_u, gl_u, zout_h, zout_l, rowst, csr_se,
                wn1h + (size_t)i * 128 * 256, wn1l + (size_t)i * 128 * 256,
                wn2h + (size_t)i * 128 * 128, wn2l + (size_t)i * 128 * 128);
        }
        k_wf_mfma<<<(4 * E2c) / 32, 512, 0, stream>>>(
            gh_u, gl_u, zout_h, zout_l, wf1h, wf1l, wf2h, wf2l, Wf3, sndr, rcvr, qh);
        // heads
        k_hl_copy<<<gE, TB, 0, stream>>>(qh, r, x, hl, hcur);
        for (int jh = 0; jh < 6; jh++) {
            float* dst = (kit == 3 && jh == 5) ? out : hnxt;
            k_head_iter<<<gN, TB, 0, stream>>>(x, hcur, hl, rowst, csr_se, dst);
            float* tmp = hcur; hcur = (kit == 3 && jh == 5) ? hcur : hnxt;
            if (!(kit == 3 && jh == 5)) hnxt = tmp;
        }
        if (kit < 3) k_flows_q<<<gE, TB, 0, stream>>>(hcur, r, sndr, rcvr, qt);
    }
}

// Round 7
// 2232.107 us; speedup vs baseline: 3.4985x; 1.1748x over previous
//
#include <hip/hip_runtime.h>
#include <hip/hip_bf16.h>
#include <math.h>

// Problem constants
#define NPGc  10000
#define EPGc  32000
#define MLc   128
#define NNc   40000      // N
#define NEc   128000     // E
#define E2c   16000      // EPG/2
#define ZETAc 1e-6f
#define INVPc 0.53995680345572354f   // 1/1.852
#define PEXPc 1.852f

typedef __attribute__((ext_vector_type(8))) short short8;   // 8 bf16 (4 VGPRs)
typedef __attribute__((ext_vector_type(4))) float f32x4;    // MFMA acc

// fast selu: __expf -> v_exp_f32
__device__ __forceinline__ float selu_f(float x) {
    float e = __expf(x) - 1.0f;
    return 1.0507009873554805f * (x > 0.0f ? x : 1.6732632423543772f * e);
}
// split fp32 -> (hi, lo) bf16 pair: v ~= hi + lo, residual ~2^-18 relative
__device__ __forceinline__ void splitu(float v, unsigned& hi, unsigned& lo) {
    __hip_bfloat16 h = __float2bfloat16(v);
    hi = (unsigned short)*reinterpret_cast<short*>(&h);
    float rem = v - __bfloat162float(h);
    __hip_bfloat16 l = __float2bfloat16(rem);
    lo = (unsigned short)*reinterpret_cast<short*>(&l);
}
__device__ __forceinline__ float signf(float x) {
    return (x > 0.0f) ? 1.0f : (x < 0.0f ? -1.0f : 0.0f);
}

// async global->LDS: 64 lanes x 4B, wave-uniform LDS base + lane*4
__device__ __forceinline__ void load_lds4(const unsigned* src, short* dst) {
    __builtin_amdgcn_global_load_lds(
        (const __attribute__((address_space(1))) unsigned*)src,
        (__attribute__((address_space(3))) unsigned*)dst, 4, 0, 0);
}

// ---------------- weight convert+split into MFMA B-FRAGMENT-LINEAR layout ------------
__global__ void k_wconv_frag(const float* __restrict__ src, short* __restrict__ dh,
                             short* __restrict__ dl, int nkc /* = K/32 */) {
    int gid = blockIdx.x * 256 + threadIdx.x;   // one thread per (frag, lane)
    int total = 8 * nkc * 64;                   // ct(8) x kc(nkc) x lane(64)
    if (gid >= total) return;
    int lane = gid & 63;
    int frag = gid >> 6;
    int kc = frag % nkc;
    int ct = frag / nkc;
    int col = ct * 16 + (lane & 15);
    int kbase = kc * 32 + (lane >> 4) * 8;
    size_t o = (size_t)gid * 8;
#pragma unroll
    for (int j = 0; j < 8; j++) {
        unsigned h, l;
        splitu(src[(size_t)(kbase + j) * 128 + col], h, l);
        dh[o + j] = (short)h;
        dl[o + j] = (short)l;
    }
}

// ---------------- CSR build (by rcvr) ----------------
__global__ void k_zero_i(int* p, int n) {
    int i = blockIdx.x * 256 + threadIdx.x;
    if (i < n) p[i] = 0;
}
__global__ void k_count(const int* __restrict__ rcvr, int* __restrict__ deg) {
    int e = blockIdx.x * 256 + threadIdx.x;
    if (e < NEc) atomicAdd(&deg[rcvr[e]], 1);
}
__global__ void k_scan(const int* __restrict__ deg, int* __restrict__ rowstart,
                       int* __restrict__ cursor) {
    __shared__ int sums[256];
    const int tid = threadIdx.x;
    const int CH = (NNc + 255) / 256;
    const int i0 = tid * CH;
    int s = 0;
    for (int j = 0; j < CH; j++) {
        int i = i0 + j;
        if (i < NNc) s += deg[i];
    }
    sums[tid] = s;
    __syncthreads();
    for (int off = 1; off < 256; off <<= 1) {
        int t = (tid >= off) ? sums[tid - off] : 0;
        __syncthreads();
        sums[tid] += t;
        __syncthreads();
    }
    int base = sums[tid] - s;
    for (int j = 0; j < CH; j++) {
        int i = i0 + j;
        if (i < NNc) {
            rowstart[i] = base;
            cursor[i] = base;
            base += deg[i];
        }
    }
    if (tid == 255) rowstart[NNc] = base;
}
__global__ void k_scatter(const int* __restrict__ sndr, const int* __restrict__ rcvr,
                          int* __restrict__ cursor, int2* __restrict__ csr_se) {
    int e = blockIdx.x * 256 + threadIdx.x;
    if (e >= NEc) return;
    int rv = rcvr[e];
    int p = atomicAdd(&cursor[rv], 1);
    csr_se[p] = make_int2(sndr[e], e);
}

// ---------------- flows / elementwise ----------------
__global__ void k_qinit(const float* __restrict__ x, const float* __restrict__ r,
                        const int* __restrict__ sndr, const int* __restrict__ rcvr,
                        float* __restrict__ qh, float* __restrict__ qt) {
    int e = blockIdx.x * 256 + threadIdx.x;
    if (e >= NEc) return;
    float hv = x[2 * sndr[e]] - x[2 * rcvr[e]];
    float q = signf(hv) * __powf((fabsf(hv) + ZETAc) / (r[e] + ZETAc), INVPc);
    qh[e] = q; qt[e] = q;
}
__global__ void k_flows_q(const float* __restrict__ h, const float* __restrict__ r,
                          const int* __restrict__ sndr, const int* __restrict__ rcvr,
                          float* __restrict__ qt) {
    int e = blockIdx.x * 256 + threadIdx.x;
    if (e >= NEc) return;
    float hv = h[sndr[e]] - h[rcvr[e]];
    qt[e] = signf(hv) * __powf((fabsf(hv) + ZETAc) / (r[e] + ZETAc), INVPc);
}

// node-in, fused segsum: one WAVE per node. Produces split-selu g planes.
__global__ __launch_bounds__(256) void k_node_in_f(
    const float* __restrict__ qh, const int* __restrict__ rowstart,
    const int2* __restrict__ csr_se, const float* __restrict__ x,
    const float* __restrict__ W /*2x128*/,
    unsigned* __restrict__ gh_u, unsigned* __restrict__ gl_u) {
    const int tid = threadIdx.x;
    const int lane = tid & 63;
    const int n = blockIdx.x * 4 + (tid >> 6);
    if (n >= NNc) return;
    int p0 = rowstart[n], p1 = rowstart[n + 1];
    float s = 0.0f;
    for (int p = p0 + lane; p < p1; p += 64) s += qh[csr_se[p].y];
#pragma unroll
    for (int off = 1; off < 64; off <<= 1) s += __shfl_xor(s, off, 64);
    float s0 = selu_f(s);
    float s1 = selu_f(x[2 * n + 1]);
    int c = lane * 2;
    float g0 = s0 * W[c]     + s1 * W[MLc + c];
    float g1 = s0 * W[c + 1] + s1 * W[MLc + c + 1];
    unsigned h0, l0, h1, l1;
    splitu(selu_f(g0), h0, l0);
    splitu(selu_f(g1), h1, l1);
    gh_u[(size_t)n * 64 + lane] = h0 | (h1 << 16);
    gl_u[(size_t)n * 64 + lane] = l0 | (l1 << 16);
}

// hl + copy_h fused
__global__ void k_hl_copy(const float* __restrict__ qh, const float* __restrict__ r,
                          const float* __restrict__ x,
                          float* __restrict__ hl, float* __restrict__ h) {
    int i = blockIdx.x * 256 + threadIdx.x;
    if (i < NEc) {
        float q = qh[i];
        hl[i] = r[i] * signf(q) * __powf(fabsf(q), PEXPc);
    }
    if (i < NNc) h[i] = x[2 * i];
}
// one head-propagation iteration, CSR gather, ping-pong (64-thread blocks: CU spread)
__global__ __launch_bounds__(64) void k_head_iter(
    const float* __restrict__ x, const float* __restrict__ hin,
    const float* __restrict__ hl, const int* __restrict__ rowstart,
    const int2* __restrict__ csr_se, float* __restrict__ hout) {
    int n = blockIdx.x * 64 + threadIdx.x;
    if (n >= NNc) return;
    float hv = hin[n];
    float m = -3.0e38f;
    int p0 = rowstart[n], p1 = rowstart[n + 1];
    for (int p = p0; p < p1; p++) {
        int2 se = csr_se[p];
        m = fmaxf(m, hin[se.x] - hl[se.y]);
    }
    float a = (m > -1e30f) ? m : hv;
    float hstar = x[2 * n];
    hout[n] = (hstar != 0.0f) ? hstar : fmaxf(hv, a);
}

// ---------------- split-bf16 MFMA MLP kernels ----------------
// Inputs arrive as pre-split selu planes (h/l shorts, 2 cols packed per dword).
// Weights fragment-linear. Staging via global_load_lds (zero-VALU data movement).
// 32-row tile, 512 threads = 8 waves; wave = 16-col tile x both 16-row tiles.
// A-frag: row=lane&15, k=quad*8+j. C/D: col=lane&15, row=quad*4+reg.

#define MS_E 392   // 384+8 shorts
#define MS_N 264   // 256+8
#define TS   136   // 128+8

__global__ __launch_bounds__(512) void k_edge_mlp_mfma(
    const unsigned* __restrict__ gh_u, const unsigned* __restrict__ gl_u,
    const unsigned* __restrict__ zh_u, const unsigned* __restrict__ zl_u,
    short* __restrict__ zoh_s, short* __restrict__ zol_s,
    const short* __restrict__ W1h, const short* __restrict__ W1l,
    const short* __restrict__ W2h, const short* __restrict__ W2l,
    const int* __restrict__ sndr, const int* __restrict__ rcvr,
    const float* __restrict__ qt, const float* __restrict__ qh,
    const float* __restrict__ Wei, int zmode) {
    __shared__ short smem[2 * 32 * MS_E];        // 50176 B
    short* m_hi = smem;
    short* m_lo = smem + 32 * MS_E;
    short* t_hi = smem;                          // alias front (post-barrier)
    short* t_lo = smem + 32 * TS;
    const int tid = threadIdx.x;
    const int e0 = blockIdx.x * 32;
    const int lane = tid & 63, wave = tid >> 6;

    // staging: (region, row) tasks via global_load_lds; region-major so task>>5/&31
    if (zmode == 0) {
        for (int t = wave; t < 96; t += 8) {
            int row = t & 31, region = t >> 5;
            int e = e0 + row;
            size_t o;
            const unsigned *ph, *pl;
            if (region == 0)      { o = (size_t)sndr[e] * 64; ph = gh_u; pl = gl_u; }
            else if (region == 1) { o = (size_t)rcvr[e] * 64; ph = gh_u; pl = gl_u; }
            else                  { o = (size_t)e * 64;       ph = zh_u; pl = zl_u; }
            load_lds4(ph + o + lane, &m_hi[row * MS_E + region * 128]);
            load_lds4(pl + o + lane, &m_lo[row * MS_E + region * 128]);
        }
    } else {
        for (int t = wave; t < 64; t += 8) {
            int row = t & 31, region = t >> 5;
            int e = e0 + row;
            size_t o = (region == 0) ? (size_t)sndr[e] * 64 : (size_t)rcvr[e] * 64;
            load_lds4(gh_u + o + lane, &m_hi[row * MS_E + region * 128]);
            load_lds4(gl_u + o + lane, &m_lo[row * MS_E + region * 128]);
        }
        for (int idx = tid; idx < 32 * 64; idx += 512) {
            int row = idx >> 6, cp = idx & 63;
            int e = e0 + row;
            float sqt = selu_f(qt[e]), sqh = selu_f(qh[e]);
            int c = 2 * cp;
            float z0 = sqt * Wei[c]     + sqh * Wei[MLc + c];
            float z1 = sqt * Wei[c + 1] + sqh * Wei[MLc + c + 1];
            unsigned h0, l0, h1, l1;
            splitu(selu_f(z0), h0, l0);
            splitu(selu_f(z1), h1, l1);
            int k = 256 + 2 * cp;
            *(unsigned*)&m_hi[row * MS_E + k] = h0 | (h1 << 16);
            *(unsigned*)&m_lo[row * MS_E + k] = l0 | (l1 << 16);
        }
    }
    __syncthreads();

    const int ct = wave;
    const int l15 = lane & 15, quad = lane >> 4;
    const int col = ct * 16 + l15;

    f32x4 acc[2];
    acc[0] = (f32x4){0.f, 0.f, 0.f, 0.f};
    acc[1] = (f32x4){0.f, 0.f, 0.f, 0.f};
#pragma unroll 4
    for (int kc = 0; kc < 12; kc++) {
        size_t wo = ((size_t)(ct * 12 + kc) * 64 + lane) * 8;   // fragment-linear
        short8 bh = *(const short8*)&W1h[wo];
        short8 bl = *(const short8*)&W1l[wo];
#pragma unroll
        for (int rt = 0; rt < 2; rt++) {
            const short* ap = &m_hi[(rt * 16 + l15) * MS_E + kc * 32 + quad * 8];
            short8 ah = *(const short8*)ap;
            short8 al = *(const short8*)(ap + 32 * MS_E);
            acc[rt] = __builtin_amdgcn_mfma_f32_16x16x32_bf16(ah, bh, acc[rt], 0, 0, 0);
            acc[rt] = __builtin_amdgcn_mfma_f32_16x16x32_bf16(al, bh, acc[rt], 0, 0, 0);
            acc[rt] = __builtin_amdgcn_mfma_f32_16x16x32_bf16(ah, bl, acc[rt], 0, 0, 0);
        }
    }
    __syncthreads();
#pragma unroll
    for (int rt = 0; rt < 2; rt++) {
#pragma unroll
        for (int rr = 0; rr < 4; rr++) {
            unsigned h, l;
            splitu(selu_f(acc[rt][rr]), h, l);
            t_hi[(rt * 16 + quad * 4 + rr) * TS + col] = (short)h;
            t_lo[(rt * 16 + quad * 4 + rr) * TS + col] = (short)l;
        }
    }
    __syncthreads();

    f32x4 acc2[2];
    acc2[0] = (f32x4){0.f, 0.f, 0.f, 0.f};
    acc2[1] = (f32x4){0.f, 0.f, 0.f, 0.f};
#pragma unroll
    for (int kc = 0; kc < 4; kc++) {
        size_t wo = ((size_t)(ct * 4 + kc) * 64 + lane) * 8;
        short8 bh = *(const short8*)&W2h[wo];
        short8 bl = *(const short8*)&W2l[wo];
#pragma unroll
        for (int rt = 0; rt < 2; rt++) {
            const short* ap = &t_hi[(rt * 16 + l15) * TS + kc * 32 + quad * 8];
            short8 ah = *(const short8*)ap;
            short8 al = *(const short8*)(ap + 32 * TS);
            acc2[rt] = __builtin_amdgcn_mfma_f32_16x16x32_bf16(ah, bh, acc2[rt], 0, 0, 0);
            acc2[rt] = __builtin_amdgcn_mfma_f32_16x16x32_bf16(al, bh, acc2[rt], 0, 0, 0);
            acc2[rt] = __builtin_amdgcn_mfma_f32_16x16x32_bf16(ah, bl, acc2[rt], 0, 0, 0);
        }
    }
    // write z output planes as 16-bit stores (same layout as packed dwords)
#pragma unroll
    for (int rt = 0; rt < 2; rt++) {
#pragma unroll
        for (int rr = 0; rr < 4; rr++) {
            unsigned h, l;
            splitu(selu_f(acc2[rt][rr]), h, l);
            size_t o = (size_t)(e0 + rt * 16 + quad * 4 + rr) * 128 + col;
            zoh_s[o] = (short)h;
            zol_s[o] = (short)l;
        }
    }
}

// node MLP: g-gather via global_load_lds + selu-space segment max of z planes
__global__ __launch_bounds__(512) void k_node_mlp_mfma(
    const unsigned* __restrict__ gh_u, const unsigned* __restrict__ gl_u,
    short* __restrict__ goh_s, short* __restrict__ gol_s,
    const unsigned* __restrict__ zh_u, const unsigned* __restrict__ zl_u,
    const int* __restrict__ rowstart, const int2* __restrict__ csr_se,
    const short* __restrict__ W1h, const short* __restrict__ W1l,
    const short* __restrict__ W2h, const short* __restrict__ W2l) {
    __shared__ short smem[2 * 32 * MS_N];        // 33792 B
    short* m_hi = smem;
    short* m_lo = smem + 32 * MS_N;
    short* t_hi = smem;
    short* t_lo = smem + 32 * TS;
    const int tid = threadIdx.x;
    const int n0 = blockIdx.x * 32;
    const int lane = tid & 63, wave = tid >> 6;

    for (int t = wave; t < 32; t += 8) {
        int n = n0 + t;
        load_lds4(gh_u + (size_t)n * 64 + lane, &m_hi[t * MS_N]);
        load_lds4(gl_u + (size_t)n * 64 + lane, &m_lo[t * MS_N]);
    }
    for (int idx = tid; idx < 32 * 64; idx += 512) {
        int row = idx >> 6, cp = idx & 63;
        int n = n0 + row;
        // segment max in selu space over CSR edges (selu monotone)
        int p0 = rowstart[n], p1 = rowstart[n + 1];
        float b0 = -3.0e38f, b1 = -3.0e38f;
        unsigned bh0 = 0, bl0 = 0, bh1 = 0, bl1 = 0;  // default split(0)
        for (int p = p0; p < p1; p++) {
            size_t o = (size_t)csr_se[p].y * 64 + cp;
            unsigned vh = zh_u[o], vl = zl_u[o];
            float f0 = __uint_as_float(vh << 16) + __uint_as_float(vl << 16);
            float f1 = __uint_as_float(vh & 0xffff0000u) + __uint_as_float(vl & 0xffff0000u);
            if (f0 > b0) { b0 = f0; bh0 = vh & 0xffffu; bl0 = vl & 0xffffu; }
            if (f1 > b1) { b1 = f1; bh1 = vh & 0xffff0000u; bl1 = vl & 0xffff0000u; }
        }
        int k = 128 + 2 * cp;
        *(unsigned*)&m_hi[row * MS_N + k] = bh0 | bh1;
        *(unsigned*)&m_lo[row * MS_N + k] = bl0 | bl1;
    }
    __syncthreads();

    const int ct = wave;
    const int l15 = lane & 15, quad = lane >> 4;
    const int col = ct * 16 + l15;

    f32x4 acc[2];
    acc[0] = (f32x4){0.f, 0.f, 0.f, 0.f};
    acc[1] = (f32x4){0.f, 0.f, 0.f, 0.f};
#pragma unroll 4
    for (int kc = 0; kc < 8; kc++) {
        size_t wo = ((size_t)(ct * 8 + kc) * 64 + lane) * 8;
        short8 bh = *(const short8*)&W1h[wo];
        short8 bl = *(const short8*)&W1l[wo];
#pragma unroll
        for (int rt = 0; rt < 2; rt++) {
            const short* ap = &m_hi[(rt * 16 + l15) * MS_N + kc * 32 + quad * 8];
            short8 ah = *(const short8*)ap;
            short8 al = *(const short8*)(ap + 32 * MS_N);
            acc[rt] = __builtin_amdgcn_mfma_f32_16x16x32_bf16(ah, bh, acc[rt], 0, 0, 0);
            acc[rt] = __builtin_amdgcn_mfma_f32_16x16x32_bf16(al, bh, acc[rt], 0, 0, 0);
            acc[rt] = __builtin_amdgcn_mfma_f32_16x16x32_bf16(ah, bl, acc[rt], 0, 0, 0);
        }
    }
    __syncthreads();
#pragma unroll
    for (int rt = 0; rt < 2; rt++) {
#pragma unroll
        for (int rr = 0; rr < 4; rr++) {
            unsigned h, l;
            splitu(selu_f(acc[rt][rr]), h, l);
            t_hi[(rt * 16 + quad * 4 + rr) * TS + col] = (short)h;
            t_lo[(rt * 16 + quad * 4 + rr) * TS + col] = (short)l;
        }
    }
    __syncthreads();

    f32x4 acc2[2];
    acc2[0] = (f32x4){0.f, 0.f, 0.f, 0.f};
    acc2[1] = (f32x4){0.f, 0.f, 0.f, 0.f};
#pragma unroll
    for (int kc = 0; kc < 4; kc++) {
        size_t wo = ((size_t)(ct * 4 + kc) * 64 + lane) * 8;
        short8 bh = *(const short8*)&W2h[wo];
        short8 bl = *(const short8*)&W2l[wo];
#pragma unroll
        for (int rt = 0; rt < 2; rt++) {
            const short* ap = &t_hi[(rt * 16 + l15) * TS + kc * 32 + quad * 8];
            short8 ah = *(const short8*)ap;
            short8 al = *(const short8*)(ap + 32 * TS);
            acc2[rt] = __builtin_amdgcn_mfma_f32_16x16x32_bf16(ah, bh, acc2[rt], 0, 0, 0);
            acc2[rt] = __builtin_amdgcn_mfma_f32_16x16x32_bf16(al, bh, acc2[rt], 0, 0, 0);
            acc2[rt] = __builtin_amdgcn_mfma_f32_16x16x32_bf16(ah, bl, acc2[rt], 0, 0, 0);
        }
    }
#pragma unroll
    for (int rt = 0; rt < 2; rt++) {
#pragma unroll
        for (int rr = 0; rr < 4; rr++) {
            unsigned h, l;
            splitu(selu_f(acc2[rt][rr]), h, l);
            size_t o = (size_t)(n0 + rt * 16 + quad * 4 + rr) * 128 + col;
            goh_s[o] = (short)h;
            gol_s[o] = (short)l;
        }
    }
}

// Wf chain on first-half edges: q_new = q_old + selu(selu(lam@Wf1)@Wf2)@Wf3; antisymmetrize.
__global__ __launch_bounds__(512) void k_wf_mfma(
    const unsigned* __restrict__ gh_u, const unsigned* __restrict__ gl_u,
    const unsigned* __restrict__ zh_u, const unsigned* __restrict__ zl_u,
    const short* __restrict__ W1h, const short* __restrict__ W1l,
    const short* __restrict__ W2h, const short* __restrict__ W2l,
    const float* __restrict__ W3 /*[128]*/,
    const int* __restrict__ sndr, const int* __restrict__ rcvr,
    float* __restrict__ qh) {
    __shared__ short smem[2 * 32 * MS_E];
    __shared__ float red[32 * 8];
    short* m_hi = smem;
    short* m_lo = smem + 32 * MS_E;
    short* t_hi = smem;
    short* t_lo = smem + 32 * TS;
    const int tid = threadIdx.x;
    const int fi0 = blockIdx.x * 32;
    const int b = fi0 / E2c;
    const int ebase = b * EPGc - b * E2c;     // e = ebase + fi
    const int lane = tid & 63, wave = tid >> 6;

    for (int t = wave; t < 96; t += 8) {
        int row = t & 31, region = t >> 5;
        int e = ebase + fi0 + row;
        size_t o;
        const unsigned *ph, *pl;
        if (region == 0)      { o = (size_t)sndr[e] * 64; ph = gh_u; pl = gl_u; }
        else if (region == 1) { o = (size_t)rcvr[e] * 64; ph = gh_u; pl = gl_u; }
        else                  { o = (size_t)e * 64;       ph = zh_u; pl = zl_u; }
        load_lds4(ph + o + lane, &m_hi[row * MS_E + region * 128]);
        load_lds4(pl + o + lane, &m_lo[row * MS_E + region * 128]);
    }
    __syncthreads();

    const int ct = wave;
    const int l15 = lane & 15, quad = lane >> 4;
    const int col = ct * 16 + l15;

    f32x4 acc[2];
    acc[0] = (f32x4){0.f, 0.f, 0.f, 0.f};
    acc[1] = (f32x4){0.f, 0.f, 0.f, 0.f};
#pragma unroll 4
    for (int kc = 0; kc < 12; kc++) {
        size_t wo = ((size_t)(ct * 12 + kc) * 64 + lane) * 8;
        short8 bh = *(const short8*)&W1h[wo];
        short8 bl = *(const short8*)&W1l[wo];
#pragma unroll
        for (int rt = 0; rt < 2; rt++) {
            const short* ap = &m_hi[(rt * 16 + l15) * MS_E + kc * 32 + quad * 8];
            short8 ah = *(const short8*)ap;
            short8 al = *(const short8*)(ap + 32 * MS_E);
            acc[rt] = __builtin_amdgcn_mfma_f32_16x16x32_bf16(ah, bh, acc[rt], 0, 0, 0);
            acc[rt] = __builtin_amdgcn_mfma_f32_16x16x32_bf16(al, bh, acc[rt], 0, 0, 0);
            acc[rt] = __builtin_amdgcn_mfma_f32_16x16x32_bf16(ah, bl, acc[rt], 0, 0, 0);
        }
    }
    __syncthreads();
#pragma unroll
    for (int rt = 0; rt < 2; rt++) {
#pragma unroll
        for (int rr = 0; rr < 4; rr++) {
            unsigned h, l;
            splitu(selu_f(acc[rt][rr]), h, l);
            t_hi[(rt * 16 + quad * 4 + rr) * TS + col] = (short)h;
            t_lo[(rt * 16 + quad * 4 + rr) * TS + col] = (short)l;
        }
    }
    __syncthreads();

    f32x4 acc2[2];
    acc2[0] = (f32x4){0.f, 0.f, 0.f, 0.f};
    acc2[1] = (f32x4){0.f, 0.f, 0.f, 0.f};
#pragma unroll
    for (int kc = 0; kc < 4; kc++) {
        size_t wo = ((size_t)(ct * 4 + kc) * 64 + lane) * 8;
        short8 bh = *(const short8*)&W2h[wo];
        short8 bl = *(const short8*)&W2l[wo];
#pragma unroll
        for (int rt = 0; rt < 2; rt++) {
            const short* ap = &t_hi[(rt * 16 + l15) * TS + kc * 32 + quad * 8];
            short8 ah = *(const short8*)ap;
            short8 al = *(const short8*)(ap + 32 * TS);
            acc2[rt] = __builtin_amdgcn_mfma_f32_16x16x32_bf16(ah, bh, acc2[rt], 0, 0, 0);
            acc2[rt] = __builtin_amdgcn_mfma_f32_16x16x32_bf16(al, bh, acc2[rt], 0, 0, 0);
            acc2[rt] = __builtin_amdgcn_mfma_f32_16x16x32_bf16(ah, bl, acc2[rt], 0, 0, 0);
        }
    }
    float w3 = W3[col];
    float p[8];
#pragma unroll
    for (int rt = 0; rt < 2; rt++)
#pragma unroll
        for (int rr = 0; rr < 4; rr++) p[rt * 4 + rr] = selu_f(acc2[rt][rr]) * w3;
#pragma unroll
    for (int off = 1; off < 16; off <<= 1) {
#pragma unroll
        for (int i = 0; i < 8; i++) p[i] += __shfl_xor(p[i], off, 64);
    }
    if (l15 == 0) {
#pragma unroll
        for (int rt = 0; rt < 2; rt++)
#pragma unroll
            for (int rr = 0; rr < 4; rr++)
                red[(rt * 16 + quad * 4 + rr) * 8 + ct] = p[rt * 4 + rr];
    }
    __syncthreads();
    if (tid < 32) {
        float f = 0.0f;
#pragma unroll
        for (int c = 0; c < 8; c++) f += red[tid * 8 + c];
        int e = ebase + fi0 + tid;
        float qn = qh[e] + f;
        qh[e] = qn;
        qh[e + E2c] = -qn;
    }
}

// ---------------- host orchestration ----------------

extern "C" void kernel_launch(void* const* d_in, const int* in_sizes, int n_in,
                              void* d_out, int out_size, void* d_ws, size_t ws_size,
                              hipStream_t stream) {
    const float* x   = (const float*)d_in[0];
    const float* r   = (const float*)d_in[1];
    const float* Wni = (const float*)d_in[2];
    const float* Wei = (const float*)d_in[3];
    const float* Wf1 = (const float*)d_in[4];
    const float* Wf2 = (const float*)d_in[5];
    const float* Wf3 = (const float*)d_in[6];
    const float* We1 = (const float*)d_in[7];   // (3,384,128)
    const float* We2 = (const float*)d_in[8];   // (3,128,128)
    const float* Wn1 = (const float*)d_in[9];   // (3,256,128)
    const float* Wn2 = (const float*)d_in[10];  // (3,128,128)
    const int* sndr  = (const int*)d_in[11];
    const int* rcvr  = (const int*)d_in[12];
    float* out = (float*)d_out;

    char* wp = (char*)d_ws;
    auto carve = [&](size_t bytes) -> void* {
        void* ret = (void*)wp;
        wp += (bytes + 255) & ~(size_t)255;
        return ret;
    };
    unsigned* gh_u = (unsigned*)carve((size_t)NNc * 64 * 4);
    unsigned* gl_u = (unsigned*)carve((size_t)NNc * 64 * 4);
    unsigned* zAh  = (unsigned*)carve((size_t)NEc * 64 * 4);
    unsigned* zAl  = (unsigned*)carve((size_t)NEc * 64 * 4);
    unsigned* zBh  = (unsigned*)carve((size_t)NEc * 64 * 4);
    unsigned* zBl  = (unsigned*)carve((size_t)NEc * 64 * 4);
    float* qh     = (float*)carve((size_t)NEc * 4);
    float* qt     = (float*)carve((size_t)NEc * 4);
    float* hl     = (float*)carve((size_t)NEc * 4);
    float* hA     = (float*)carve((size_t)NNc * 4);
    float* hB     = (float*)carve((size_t)NNc * 4);
    int*   deg    = (int*)carve((size_t)NNc * 4);
    int*   cursor = (int*)carve((size_t)NNc * 4);
    int*   rowst  = (int*)carve((size_t)(NNc + 1) * 4);
    int2*  csr_se = (int2*)carve((size_t)NEc * 8);
    short* we1h   = (short*)carve((size_t)3 * 128 * 384 * 2);
    short* we1l   = (short*)carve((size_t)3 * 128 * 384 * 2);
    short* we2h   = (short*)carve((size_t)3 * 128 * 128 * 2);
    short* we2l   = (short*)carve((size_t)3 * 128 * 128 * 2);
    short* wn1h   = (short*)carve((size_t)3 * 128 * 256 * 2);
    short* wn1l   = (short*)carve((size_t)3 * 128 * 256 * 2);
    short* wn2h   = (short*)carve((size_t)3 * 128 * 128 * 2);
    short* wn2l   = (short*)carve((size_t)3 * 128 * 128 * 2);
    short* wf1h   = (short*)carve((size_t)128 * 384 * 2);
    short* wf1l   = (short*)carve((size_t)128 * 384 * 2);
    short* wf2h   = (short*)carve((size_t)128 * 128 * 2);
    short* wf2l   = (short*)carve((size_t)128 * 128 * 2);

    const int TB = 256;
    const int gN  = (NNc + TB - 1) / TB;
    const int gE  = (NEc + TB - 1) / TB;

    // fragment-linear weight planes (nkc = K/32)
    for (int i = 0; i < 3; i++) {
        k_wconv_frag<<<(8 * 12 * 64 + 255) / 256, TB, 0, stream>>>(We1 + (size_t)i * 384 * 128, we1h + (size_t)i * 128 * 384, we1l + (size_t)i * 128 * 384, 12);
        k_wconv_frag<<<(8 * 4 * 64 + 255) / 256, TB, 0, stream>>>(We2 + (size_t)i * 128 * 128, we2h + (size_t)i * 128 * 128, we2l + (size_t)i * 128 * 128, 4);
        k_wconv_frag<<<(8 * 8 * 64 + 255) / 256, TB, 0, stream>>>(Wn1 + (size_t)i * 256 * 128, wn1h + (size_t)i * 128 * 256, wn1l + (size_t)i * 128 * 256, 8);
        k_wconv_frag<<<(8 * 4 * 64 + 255) / 256, TB, 0, stream>>>(Wn2 + (size_t)i * 128 * 128, wn2h + (size_t)i * 128 * 128, wn2l + (size_t)i * 128 * 128, 4);
    }
    k_wconv_frag<<<(8 * 12 * 64 + 255) / 256, TB, 0, stream>>>(Wf1, wf1h, wf1l, 12);
    k_wconv_frag<<<(8 * 4 * 64 + 255) / 256, TB, 0, stream>>>(Wf2, wf2h, wf2l, 4);

    // CSR build
    k_zero_i<<<gN, TB, 0, stream>>>(deg, NNc);
    k_count<<<gE, TB, 0, stream>>>(rcvr, deg);
    k_scan<<<1, TB, 0, stream>>>(deg, rowst, cursor);
    k_scatter<<<gE, TB, 0, stream>>>(sndr, rcvr, cursor, csr_se);

    // initial flows
    k_qinit<<<gE, TB, 0, stream>>>(x, r, sndr, rcvr, qh, qt);

    float* hcur = hA;
    float* hnxt = hB;
    for (int kit = 0; kit < 4; kit++) {
        // g = split-selu planes of selu([segsum(qh), d_star]) @ Wni
        k_node_in_f<<<(NNc + 3) / 4, TB, 0, stream>>>(qh, rowst, csr_se, x, Wni, gh_u, gl_u);
        // edge/node message-passing layers; z planes ping-pong A<->B
        unsigned *zin_h = zAh, *zin_l = zAl, *zout_h = zAh, *zout_l = zAl;
        for (int i = 0; i < 3; i++) {
            zin_h = zout_h; zin_l = zout_l;
            zout_h = (i & 1) ? zAh : zBh;
            zout_l = (i & 1) ? zAl : zBl;
            k_edge_mlp_mfma<<<NEc / 32, 512, 0, stream>>>(
                gh_u, gl_u, zin_h, zin_l, (short*)zout_h, (short*)zout_l,
                we1h + (size_t)i * 128 * 384, we1l + (size_t)i * 128 * 384,
                we2h + (size_t)i * 128 * 128, we2l + (size_t)i * 128 * 128,
                sndr, rcvr, qt, qh, Wei, (i == 0) ? 1 : 0);
            k_node_mlp_mfma<<<NNc / 32, 512, 0, stream>>>(
                gh_u, gl_u, (short*)gh_u, (short*)gl_u, zout_h, zout_l, rowst, csr_se,
                wn1h + (size_t)i * 128 * 256, wn1l + (size_t)i * 128 * 256,
                wn2h + (size_t)i * 128 * 128, wn2l + (size_t)i * 128 * 128);
        }
        k_wf_mfma<<<(4 * E2c) / 32, 512, 0, stream>>>(
            gh_u, gl_u, zout_h, zout_l, wf1h, wf1l, wf2h, wf2l, Wf3, sndr, rcvr, qh);
        // heads
        k_hl_copy<<<gE, TB, 0, stream>>>(qh, r, x, hl, hcur);
        for (int jh = 0; jh < 6; jh++) {
            float* dst = (kit == 3 && jh == 5) ? out : hnxt;
            k_head_iter<<<(NNc + 63) / 64, 64, 0, stream>>>(x, hcur, hl, rowst, csr_se, dst);
            float* tmp = hcur; hcur = (kit == 3 && jh == 5) ? hcur : hnxt;
            if (!(kit == 3 && jh == 5)) hnxt = tmp;
        }
        if (kit < 3) k_flows_q<<<gE, TB, 0, stream>>>(hcur, r, sndr, rcvr, qt);
    }
}